// Round 6
// baseline (229.694 us; speedup 1.0000x reference)
//
#include <hip/hip_runtime.h>
#include <math.h>

#define Hd 128
#define Wd 128
#define HW 16384      // 128*128
#define EPSc 1e-6f

typedef __attribute__((ext_vector_type(8))) short s8v;    // 8 bf16 (4 VGPRs)
typedef __attribute__((ext_vector_type(4))) float f4v;    // 4 fp32 acc

__device__ __forceinline__ unsigned short f2bf(float f) {
    unsigned int u = __float_as_uint(f);
    unsigned int r = (u + 0x7FFFu + ((u >> 16) & 1u)) >> 16;   // RNE
    return (unsigned short)r;
}

// ---------------------------------------------------------------------------
// K0: fused weight prep + cm zero + x NCHW->NHWC bf16.
// blocks 0..127: xh transform. blocks 128..589: weight prep / cm zero.
__global__ void k_prepxh(const float* __restrict__ x,
                         const float* __restrict__ ga_w1, const float* __restrict__ ga_w2,
                         const float* __restrict__ cd_w1,
                         const float* __restrict__ ec_w1, const float* __restrict__ ec_w2,
                         unsigned short* __restrict__ xh,
                         float* __restrict__ ga_w1t, float* __restrict__ ga_w2t,
                         float* __restrict__ cd_w1t,
                         unsigned short* __restrict__ w1h, unsigned short* __restrict__ w2h,
                         float* __restrict__ cm) {
    int bid = blockIdx.x;
    if (bid < 128) {
        int p = bid * 256 + threadIdx.x;   // 0..32767
        int b = p >> 14, s = p & (HW - 1);
        const float* xp = x + (size_t)b * 64 * HW + s;
        alignas(16) unsigned short buf[64];
#pragma unroll
        for (int c = 0; c < 64; c++) buf[c] = f2bf(xp[c * HW]);
        uint4* dst = (uint4*)(xh + (size_t)p * 64);
        const uint4* src = (const uint4*)buf;
#pragma unroll
        for (int i = 0; i < 8; i++) dst[i] = src[i];
        return;
    }
    int i = (bid - 128) * 256 + threadIdx.x;
    if (i < 36864) {                               // w1h [t][co][ci]
        int t = i >> 12, co = (i >> 6) & 63, ci = i & 63;
        w1h[i] = f2bf(ec_w1[(co * 64 + ci) * 9 + t]);
    } else if (i < 73728) {                        // w2h
        int j = i - 36864;
        int t = j >> 12, co = (j >> 6) & 63, ci = j & 63;
        w2h[j] = f2bf(ec_w2[(co * 64 + ci) * 9 + t]);
    } else if (i < 81920) {                        // ga_w1t [ci128][co64]
        int j = i - 73728;
        int co = j & 63, ci = j >> 6;
        ga_w1t[j] = ga_w1[co * 128 + ci];
    } else if (i < 82944) {                        // ga_w2t [ci64][co16]
        int j = i - 81920;
        int co = j & 15, ci = j >> 4;
        ga_w2t[j] = ga_w2[co * 64 + ci];
    } else if (i < 85248) {                        // cd_w1t [ci16][tap9][co16]
        int j = i - 82944;
        int co = j & 15, r = j >> 4, t = r % 9, ci = r / 9;
        cd_w1t[j] = cd_w1[(co * 16 + ci) * 9 + t];
    } else if (i < 118016) {                       // cm zero
        cm[i - 85248] = 0.f;
    }
}

// ---------------------------------------------------------------------------
// K1: fused sobel + 5x5 weighted circular-variance + channel-mean.
// 16x16 tile, 4 channels per block. grid (8,8,32): z = b*16 + cq.
// 8 blocks/CU (32 waves); lm/ld stride 24 (2-way banks = free).
__global__ __launch_bounds__(256, 8)
void k_sobcons(const float* __restrict__ x,
               const float* __restrict__ wgx, const float* __restrict__ wgy,
               float* __restrict__ gx, float* __restrict__ gy,
               float* __restrict__ cm) {
    __shared__ float xt[484];        // 22x22 x-tile (3-halo)
    __shared__ float lm[480];        // 20 rows x stride 24
    __shared__ float ld[480];
    int tid = threadIdx.x;
    int tx = tid & 15, ty = tid >> 4;
    int x0 = blockIdx.x * 16, y0 = blockIdx.y * 16;
    int b = blockIdx.z >> 4, cb = (blockIdx.z & 15) * 4;
    float acc = 0.f;
    for (int c = 0; c < 4; c++) {
        int ch = cb + c;
        const float* xp = x + (size_t)(b * 64 + ch) * HW;
        float wx[9], wy[9];
#pragma unroll
        for (int i = 0; i < 9; i++) { wx[i] = wgx[ch * 9 + i]; wy[i] = wgy[ch * 9 + i]; }
        __syncthreads();    // previous channel's cons reads done
        for (int i = tid; i < 484; i += 256) {
            int yy = i / 22, xx = i - yy * 22;
            int gyy = y0 - 3 + yy, gxx = x0 - 3 + xx;
            xt[i] = (gyy >= 0 && gyy < Hd && gxx >= 0 && gxx < Wd) ? xp[gyy * Wd + gxx] : 0.f;
        }
        __syncthreads();
        for (int i = tid; i < 400; i += 256) {
            int yy = i / 20, xx = i - yy * 20;      // point (y0-2+yy, x0-2+xx)
            int gyy = y0 - 2 + yy, gxx = x0 - 2 + xx;
            float m = 0.f, d = 0.f, sx = 0.f, sy = 0.f;
            if (gyy >= 0 && gyy < Hd && gxx >= 0 && gxx < Wd) {
#pragma unroll
                for (int dy = 0; dy < 3; dy++)
#pragma unroll
                    for (int dx = 0; dx < 3; dx++) {
                        float v = xt[(yy + dy) * 22 + xx + dx];
                        sx = fmaf(wx[dy * 3 + dx], v, sx);
                        sy = fmaf(wy[dy * 3 + dx], v, sy);
                    }
                m = sqrtf(sx * sx + sy * sy + EPSc);
                d = atan2f(sy, sx);
            }
            lm[yy * 24 + xx] = m;
            ld[yy * 24 + xx] = d;
            if (yy >= 2 && yy < 18 && xx >= 2 && xx < 18) {
                int o = (b * 64 + ch) * HW + gyy * Wd + gxx;
                gx[o] = sx;
                gy[o] = sy;
            }
        }
        __syncthreads();
        float mv[25], dv[25];
        float sm = 0.f, sdm = 0.f;
#pragma unroll
        for (int r = 0; r < 5; r++)
#pragma unroll
            for (int cx = 0; cx < 5; cx++) {
                int idx = (ty + r) * 24 + tx + cx;
                float m = lm[idx], d = ld[idx];
                mv[r * 5 + cx] = m;
                dv[r * 5 + cx] = d;
                sm += m;
                sdm = fmaf(d, m, sdm);
            }
        float wmean = sdm / (sm + EPSc);
        float sv = 0.f;
#pragma unroll
        for (int t = 0; t < 25; t++) { float dd = dv[t] - wmean; sv = fmaf(dd * dd, mv[t], sv); }
        float wstd = sqrtf(sv / (sm + EPSc));
        acc += 1.f - tanhf(wstd);
    }
    atomicAdd(&cm[b * HW + (y0 + ty) * Wd + x0 + tx], acc * (1.f / 64.f));
}

// ---------------------------------------------------------------------------
// K2: fused ga1+ga2 (both 1x1 convs are per-pixel -> fuse in-thread).
// One thread per pixel: a1[64] = relu(W1·[gx;gy]+b1); ga2 = relu(W2·a1+b2).
// No ga1 round-trip, no redundant gx/gy reads. grid 512 x block 64.
__global__ __launch_bounds__(64, 4)
void k_ga12(const float* __restrict__ gx, const float* __restrict__ gy,
            const float* __restrict__ w1t, const float* __restrict__ b1,
            const float* __restrict__ w2t, const float* __restrict__ b2,
            float* __restrict__ ga2) {
    int p = blockIdx.x * 64 + threadIdx.x;   // 0..32767
    int b = p >> 14;
    int s = p & (HW - 1);
    const float* gxp = gx + (size_t)b * 64 * HW + s;
    const float* gyp = gy + (size_t)b * 64 * HW + s;
    float a1[64];
#pragma unroll
    for (int co = 0; co < 64; co++) a1[co] = b1[co];
#pragma unroll 4
    for (int ci = 0; ci < 64; ci++) {
        float v = gxp[ci * HW];
        const float* wp = w1t + ci * 64;
#pragma unroll
        for (int co = 0; co < 64; co++) a1[co] = fmaf(v, wp[co], a1[co]);
    }
#pragma unroll 4
    for (int ci = 0; ci < 64; ci++) {
        float v = gyp[ci * HW];
        const float* wp = w1t + (64 + ci) * 64;
#pragma unroll
        for (int co = 0; co < 64; co++) a1[co] = fmaf(v, wp[co], a1[co]);
    }
    float a2[16];
#pragma unroll
    for (int co = 0; co < 16; co++) a2[co] = b2[co];
#pragma unroll 4
    for (int ci = 0; ci < 64; ci++) {
        float v = fmaxf(a1[ci], 0.f);
        const float* wp = w2t + ci * 16;
#pragma unroll
        for (int co = 0; co < 16; co++) a2[co] = fmaf(v, wp[co], a2[co]);
    }
    float* op = ga2 + (size_t)b * 16 * HW + s;
#pragma unroll
    for (int co = 0; co < 16; co++) op[co * HW] = fmaxf(a2[co], 0.f);
}

// ---------------------------------------------------------------------------
// K5+K6 fused: 3x3 conv [16][16] + relu + 1x1 [1][16] + sigmoid, * cm -> ew
// grid (8,8,2), block 256.
__global__ __launch_bounds__(256, 4)
void k_cd1ew(const float* __restrict__ ga2, const float* __restrict__ w1t,
             const float* __restrict__ b1, const float* __restrict__ w2,
             const float* __restrict__ b2, const float* __restrict__ cm,
             float* __restrict__ ew) {
    __shared__ float lds[16][324];
    int tid = threadIdx.x;
    int tx = tid & 15, ty = tid >> 4;
    int x0 = blockIdx.x * 16, y0 = blockIdx.y * 16;
    int b = blockIdx.z;
    const float* ip = ga2 + (size_t)b * 16 * HW;
    float acc[16];
#pragma unroll
    for (int co = 0; co < 16; co++) acc[co] = b1[co];
#pragma unroll
    for (int ci = 0; ci < 16; ci++) {
        const float* sp = ip + ci * HW;
        for (int i = tid; i < 324; i += 256) {
            int yy = i / 18, xx = i - yy * 18;
            int gy = y0 - 1 + yy, gx = x0 - 1 + xx;
            lds[ci][i] = (gy >= 0 && gy < Hd && gx >= 0 && gx < Wd) ? sp[gy * Wd + gx] : 0.f;
        }
    }
    __syncthreads();
    for (int ci = 0; ci < 16; ci++) {
        const float* wp = w1t + ci * 9 * 16;
        float pv[9];
#pragma unroll
        for (int r = 0; r < 3; r++)
#pragma unroll
            for (int cx = 0; cx < 3; cx++)
                pv[r * 3 + cx] = lds[ci][(ty + r) * 18 + tx + cx];
#pragma unroll
        for (int t = 0; t < 9; t++)
#pragma unroll
            for (int co = 0; co < 16; co++)
                acc[co] = fmaf(pv[t], wp[t * 16 + co], acc[co]);
    }
    float e = b2[0];
#pragma unroll
    for (int co = 0; co < 16; co++) e = fmaf(fmaxf(acc[co], 0.f), w2[co], e);
    float sig = 1.f / (1.f + expf(-e));
    int sp = (y0 + ty) * Wd + x0 + tx;
    ew[b * HW + sp] = sig * cm[b * HW + sp];
}

// ---------------------------------------------------------------------------
// K7/K8: 3x3 conv [64][64] via bf16 MFMA implicit GEMM, tap-split.
// 8x8 output tile x 64 co, 4 waves (wave w -> co 16w..16w+15).
// LDS: 10x10x64 bf16 halo tile, ci-octet XOR-swizzled vs (rowlin&7).
// FINAL=0: relu -> bf16 NHWC out. FINAL=1: out = x + alpha*ew*acc (fp32 NCHW).
template <int FINAL>
__global__ __launch_bounds__(256, 2)
void k_conv64m(const unsigned short* __restrict__ inh,
               const unsigned short* __restrict__ wh,
               const float* __restrict__ bias,
               unsigned short* __restrict__ outh,
               float* __restrict__ outf,
               const float* __restrict__ x,
               const float* __restrict__ ew,
               const float* __restrict__ alpha_p) {
    __shared__ unsigned short tile[100 * 64];   // 12.8 KB
    int tid = threadIdx.x;
    int x0 = blockIdx.x * 8, y0 = blockIdx.y * 8;
    int b = blockIdx.z;
    const size_t ibase = (size_t)b * HW * 64;

    for (int i = tid; i < 800; i += 256) {
        int py = i / 80;
        int r = i - py * 80;
        int px = r >> 3, cg = r & 7;
        int gy = y0 - 1 + py, gx = x0 - 1 + px;
        uint4 v = {0u, 0u, 0u, 0u};
        if (gy >= 0 && gy < Hd && gx >= 0 && gx < Wd)
            v = *(const uint4*)(inh + ibase + (size_t)(gy * Wd + gx) * 64 + cg * 8);
        int rowlin = py * 10 + px;
        int scg = cg ^ (rowlin & 7);
        *(uint4*)(tile + rowlin * 64 + scg * 8) = v;
    }

    int lane = tid & 63;
    int wv = tid >> 6;
    int l15 = lane & 15, lq = lane >> 4;
    int co_base = wv * 16;

    s8v af[9][2];
#pragma unroll
    for (int t = 0; t < 9; t++)
#pragma unroll
        for (int h = 0; h < 2; h++)
            af[t][h] = *(const s8v*)(wh + ((t * 64 + co_base + l15) * 64 + h * 32 + lq * 8));

    f4v bv = *(const f4v*)(bias + co_base + lq * 4);
    f4v acc[4];
#pragma unroll
    for (int n = 0; n < 4; n++) acc[n] = bv;

    __syncthreads();

#pragma unroll
    for (int n = 0; n < 4; n++) {
        int px = n * 16 + l15;
        int pyy = px >> 3, pxx = px & 7;
#pragma unroll
        for (int dy = 0; dy < 3; dy++) {
#pragma unroll
            for (int dx = 0; dx < 3; dx++) {
                int rowlin = (pyy + dy) * 10 + (pxx + dx);
                int sw = rowlin & 7;
                const unsigned short* tp = tile + rowlin * 64;
                s8v b0 = *(const s8v*)(tp + (lq ^ sw) * 8);
                s8v b1 = *(const s8v*)(tp + ((4 + lq) ^ sw) * 8);
                int t = dy * 3 + dx;
                acc[n] = __builtin_amdgcn_mfma_f32_16x16x32_bf16(af[t][0], b0, acc[n], 0, 0, 0);
                acc[n] = __builtin_amdgcn_mfma_f32_16x16x32_bf16(af[t][1], b1, acc[n], 0, 0, 0);
            }
        }
    }

#pragma unroll
    for (int n = 0; n < 4; n++) {
        int px = n * 16 + l15;
        int gyo = y0 + (px >> 3), gxo = x0 + (px & 7);
        int sp = gyo * Wd + gxo;
        if (FINAL) {
            float ae = alpha_p[0] * ew[b * HW + sp];
#pragma unroll
            for (int r = 0; r < 4; r++) {
                size_t o = (size_t)(b * 64 + co_base + lq * 4 + r) * HW + sp;
                outf[o] = fmaf(ae, acc[n][r], x[o]);
            }
        } else {
            alignas(8) unsigned short pk[4];
#pragma unroll
            for (int r = 0; r < 4; r++) pk[r] = f2bf(fmaxf(acc[n][r], 0.f));
            *(uint2*)(outh + ibase + (size_t)sp * 64 + co_base + lq * 4) = *(const uint2*)pk;
        }
    }
}

// ---------------------------------------------------------------------------
extern "C" void kernel_launch(void* const* d_in, const int* in_sizes, int n_in,
                              void* d_out, int out_size, void* d_ws, size_t ws_size,
                              hipStream_t stream) {
    const float* x     = (const float*)d_in[0];
    const float* wgx   = (const float*)d_in[1];
    const float* wgy   = (const float*)d_in[2];
    const float* ga_w1 = (const float*)d_in[3];
    const float* ga_b1 = (const float*)d_in[4];
    const float* ga_w2 = (const float*)d_in[5];
    const float* ga_b2 = (const float*)d_in[6];
    const float* cd_w1 = (const float*)d_in[7];
    const float* cd_b1 = (const float*)d_in[8];
    const float* cd_w2 = (const float*)d_in[9];
    const float* cd_b2 = (const float*)d_in[10];
    const float* ec_w1 = (const float*)d_in[11];
    const float* ec_b1 = (const float*)d_in[12];
    const float* ec_w2 = (const float*)d_in[13];
    const float* ec_b2 = (const float*)d_in[14];
    const float* alpha = (const float*)d_in[15];
    float* out = (float*)d_out;
    float* ws  = (float*)d_ws;

    const size_t N = 2 * 64 * HW;   // 2,097,152 floats

    // buffer plan:
    float* gx    = ws;               // N
    float* gy    = ws + N;           // N
    float* ga2   = ws + 3 * N;                    // 524288 floats
    float* cm    = ga2 + 2 * 16 * HW;             // 32768
    float* ew    = cm + 2 * HW;                   // 32768
    float* ga_w1t = ew + 2 * HW;                  // 8192
    float* ga_w2t = ga_w1t + 8192;                // 1024
    float* cd_w1t = ga_w2t + 1024;                // 2304
    unsigned short* w1h = (unsigned short*)(cd_w1t + 2304);  // 36864 shorts
    unsigned short* w2h = w1h + 36864;                       // 36864 shorts
    unsigned short* xh   = (unsigned short*)(ws + 4 * N);    // 2M shorts
    unsigned short* ee1h = xh + N;                           // 2M shorts

    k_prepxh<<<590, 256, 0, stream>>>(x, ga_w1, ga_w2, cd_w1, ec_w1, ec_w2,
                                      xh, ga_w1t, ga_w2t, cd_w1t, w1h, w2h, cm);
    k_sobcons<<<dim3(8, 8, 32), 256, 0, stream>>>(x, wgx, wgy, gx, gy, cm);
    k_ga12<<<512, 64, 0, stream>>>(gx, gy, ga_w1t, ga_b1, ga_w2t, ga_b2, ga2);
    k_cd1ew<<<dim3(8, 8, 2), 256, 0, stream>>>(ga2, cd_w1t, cd_b1, cd_w2, cd_b2, cm, ew);
    k_conv64m<0><<<dim3(16, 16, 2), 256, 0, stream>>>(xh, w1h, ec_b1, ee1h,
                                                      nullptr, nullptr, nullptr, nullptr);
    k_conv64m<1><<<dim3(16, 16, 2), 256, 0, stream>>>(ee1h, w2h, ec_b2, nullptr,
                                                      out, x, ew, alpha);
}

// Round 7
// 210.934 us; speedup vs baseline: 1.0889x; 1.0889x over previous
//
#include <hip/hip_runtime.h>
#include <math.h>

#define Hd 128
#define Wd 128
#define HW 16384      // 128*128
#define EPSc 1e-6f

typedef __attribute__((ext_vector_type(8))) short s8v;    // 8 bf16 (4 VGPRs)
typedef __attribute__((ext_vector_type(4))) float f4v;    // 4 fp32 acc

__device__ __forceinline__ unsigned short f2bf(float f) {
    unsigned int u = __float_as_uint(f);
    unsigned int r = (u + 0x7FFFu + ((u >> 16) & 1u)) >> 16;   // RNE
    return (unsigned short)r;
}

// ---------------------------------------------------------------------------
// K0: fused weight prep + cm zero + x NCHW->NHWC bf16.
// blocks 0..127: xh transform. blocks 128..589: weight prep / cm zero.
__global__ void k_prepxh(const float* __restrict__ x,
                         const float* __restrict__ ga_w1, const float* __restrict__ ga_w2,
                         const float* __restrict__ cd_w1,
                         const float* __restrict__ ec_w1, const float* __restrict__ ec_w2,
                         unsigned short* __restrict__ xh,
                         float* __restrict__ ga_w1t, float* __restrict__ ga_w2t,
                         float* __restrict__ cd_w1t,
                         unsigned short* __restrict__ w1h, unsigned short* __restrict__ w2h,
                         float* __restrict__ cm) {
    int bid = blockIdx.x;
    if (bid < 128) {
        int p = bid * 256 + threadIdx.x;   // 0..32767
        int b = p >> 14, s = p & (HW - 1);
        const float* xp = x + (size_t)b * 64 * HW + s;
        alignas(16) unsigned short buf[64];
#pragma unroll
        for (int c = 0; c < 64; c++) buf[c] = f2bf(xp[c * HW]);
        uint4* dst = (uint4*)(xh + (size_t)p * 64);
        const uint4* src = (const uint4*)buf;
#pragma unroll
        for (int i = 0; i < 8; i++) dst[i] = src[i];
        return;
    }
    int i = (bid - 128) * 256 + threadIdx.x;
    if (i < 36864) {                               // w1h [t][co][ci]
        int t = i >> 12, co = (i >> 6) & 63, ci = i & 63;
        w1h[i] = f2bf(ec_w1[(co * 64 + ci) * 9 + t]);
    } else if (i < 73728) {                        // w2h
        int j = i - 36864;
        int t = j >> 12, co = (j >> 6) & 63, ci = j & 63;
        w2h[j] = f2bf(ec_w2[(co * 64 + ci) * 9 + t]);
    } else if (i < 81920) {                        // ga_w1t [ci128][co64]
        int j = i - 73728;
        int co = j & 63, ci = j >> 6;
        ga_w1t[j] = ga_w1[co * 128 + ci];
    } else if (i < 82944) {                        // ga_w2t [ci64][co16]
        int j = i - 81920;
        int co = j & 15, ci = j >> 4;
        ga_w2t[j] = ga_w2[co * 64 + ci];
    } else if (i < 85248) {                        // cd_w1t [ci16][tap9][co16]
        int j = i - 82944;
        int co = j & 15, r = j >> 4, t = r % 9, ci = r / 9;
        cd_w1t[j] = cd_w1[(co * 16 + ci) * 9 + t];
    } else if (i < 118016) {                       // cm zero
        cm[i - 85248] = 0.f;
    }
}

// ---------------------------------------------------------------------------
// K1: fused sobel + 5x5 weighted circular-variance + channel-mean.
// 16x16 tile, 4 channels per block. grid (8,8,32): z = b*16 + cq.
// 8 blocks/CU (32 waves); lm/ld stride 24 (2-way banks = free).
__global__ __launch_bounds__(256, 8)
void k_sobcons(const float* __restrict__ x,
               const float* __restrict__ wgx, const float* __restrict__ wgy,
               float* __restrict__ gx, float* __restrict__ gy,
               float* __restrict__ cm) {
    __shared__ float xt[484];        // 22x22 x-tile (3-halo)
    __shared__ float lm[480];        // 20 rows x stride 24
    __shared__ float ld[480];
    int tid = threadIdx.x;
    int tx = tid & 15, ty = tid >> 4;
    int x0 = blockIdx.x * 16, y0 = blockIdx.y * 16;
    int b = blockIdx.z >> 4, cb = (blockIdx.z & 15) * 4;
    float acc = 0.f;
    for (int c = 0; c < 4; c++) {
        int ch = cb + c;
        const float* xp = x + (size_t)(b * 64 + ch) * HW;
        float wx[9], wy[9];
#pragma unroll
        for (int i = 0; i < 9; i++) { wx[i] = wgx[ch * 9 + i]; wy[i] = wgy[ch * 9 + i]; }
        __syncthreads();    // previous channel's cons reads done
        for (int i = tid; i < 484; i += 256) {
            int yy = i / 22, xx = i - yy * 22;
            int gyy = y0 - 3 + yy, gxx = x0 - 3 + xx;
            xt[i] = (gyy >= 0 && gyy < Hd && gxx >= 0 && gxx < Wd) ? xp[gyy * Wd + gxx] : 0.f;
        }
        __syncthreads();
        for (int i = tid; i < 400; i += 256) {
            int yy = i / 20, xx = i - yy * 20;      // point (y0-2+yy, x0-2+xx)
            int gyy = y0 - 2 + yy, gxx = x0 - 2 + xx;
            float m = 0.f, d = 0.f, sx = 0.f, sy = 0.f;
            if (gyy >= 0 && gyy < Hd && gxx >= 0 && gxx < Wd) {
#pragma unroll
                for (int dy = 0; dy < 3; dy++)
#pragma unroll
                    for (int dx = 0; dx < 3; dx++) {
                        float v = xt[(yy + dy) * 22 + xx + dx];
                        sx = fmaf(wx[dy * 3 + dx], v, sx);
                        sy = fmaf(wy[dy * 3 + dx], v, sy);
                    }
                m = sqrtf(sx * sx + sy * sy + EPSc);
                d = atan2f(sy, sx);
            }
            lm[yy * 24 + xx] = m;
            ld[yy * 24 + xx] = d;
            if (yy >= 2 && yy < 18 && xx >= 2 && xx < 18) {
                int o = (b * 64 + ch) * HW + gyy * Wd + gxx;
                gx[o] = sx;
                gy[o] = sy;
            }
        }
        __syncthreads();
        float mv[25], dv[25];
        float sm = 0.f, sdm = 0.f;
#pragma unroll
        for (int r = 0; r < 5; r++)
#pragma unroll
            for (int cx = 0; cx < 5; cx++) {
                int idx = (ty + r) * 24 + tx + cx;
                float m = lm[idx], d = ld[idx];
                mv[r * 5 + cx] = m;
                dv[r * 5 + cx] = d;
                sm += m;
                sdm = fmaf(d, m, sdm);
            }
        float wmean = sdm / (sm + EPSc);
        float sv = 0.f;
#pragma unroll
        for (int t = 0; t < 25; t++) { float dd = dv[t] - wmean; sv = fmaf(dd * dd, mv[t], sv); }
        float wstd = sqrtf(sv / (sm + EPSc));
        acc += 1.f - tanhf(wstd);
    }
    atomicAdd(&cm[b * HW + (y0 + ty) * Wd + x0 + tx], acc * (1.f / 64.f));
}

// ---------------------------------------------------------------------------
// K2: fused ga1+ga2, one thread per pixel.
// CRITICAL: every a1[] index must be a compile-time constant (full unroll of
// the a2 ci-loop) or the compiler demotes a1[64] to scratch (round-6: VGPR=40,
// 73 us). launch_bounds(64,2) caps VGPR at 256 so the ~110-reg set fits.
__global__ __launch_bounds__(64, 2)
void k_ga12(const float* __restrict__ gx, const float* __restrict__ gy,
            const float* __restrict__ w1t, const float* __restrict__ b1,
            const float* __restrict__ w2t, const float* __restrict__ b2,
            float* __restrict__ ga2) {
    int p = blockIdx.x * 64 + threadIdx.x;   // 0..32767
    int b = p >> 14;
    int s = p & (HW - 1);
    const float* gxp = gx + (size_t)b * 64 * HW + s;
    const float* gyp = gy + (size_t)b * 64 * HW + s;
    float a1[64];
#pragma unroll
    for (int co = 0; co < 64; co++) a1[co] = b1[co];
#pragma unroll 4
    for (int ci = 0; ci < 64; ci++) {
        float v = gxp[ci * HW];
        const float* wp = w1t + ci * 64;
#pragma unroll
        for (int co = 0; co < 64; co++) a1[co] = fmaf(v, wp[co], a1[co]);
    }
#pragma unroll 4
    for (int ci = 0; ci < 64; ci++) {
        float v = gyp[ci * HW];
        const float* wp = w1t + (64 + ci) * 64;
#pragma unroll
        for (int co = 0; co < 64; co++) a1[co] = fmaf(v, wp[co], a1[co]);
    }
    float a2[16];
#pragma unroll
    for (int co = 0; co < 16; co++) a2[co] = b2[co];
#pragma unroll
    for (int ci = 0; ci < 64; ci++) {      // FULL unroll: a1[ci] stays constant-indexed
        float v = fmaxf(a1[ci], 0.f);
        const float* wp = w2t + ci * 16;
#pragma unroll
        for (int co = 0; co < 16; co++) a2[co] = fmaf(v, wp[co], a2[co]);
    }
    float* op = ga2 + (size_t)b * 16 * HW + s;
#pragma unroll
    for (int co = 0; co < 16; co++) op[co * HW] = fmaxf(a2[co], 0.f);
}

// ---------------------------------------------------------------------------
// K5+K6 fused: 3x3 conv [16][16] + relu + 1x1 [1][16] + sigmoid, * cm -> ew
// grid (8,8,2), block 256.
__global__ __launch_bounds__(256, 4)
void k_cd1ew(const float* __restrict__ ga2, const float* __restrict__ w1t,
             const float* __restrict__ b1, const float* __restrict__ w2,
             const float* __restrict__ b2, const float* __restrict__ cm,
             float* __restrict__ ew) {
    __shared__ float lds[16][324];
    int tid = threadIdx.x;
    int tx = tid & 15, ty = tid >> 4;
    int x0 = blockIdx.x * 16, y0 = blockIdx.y * 16;
    int b = blockIdx.z;
    const float* ip = ga2 + (size_t)b * 16 * HW;
    float acc[16];
#pragma unroll
    for (int co = 0; co < 16; co++) acc[co] = b1[co];
#pragma unroll
    for (int ci = 0; ci < 16; ci++) {
        const float* sp = ip + ci * HW;
        for (int i = tid; i < 324; i += 256) {
            int yy = i / 18, xx = i - yy * 18;
            int gy = y0 - 1 + yy, gx = x0 - 1 + xx;
            lds[ci][i] = (gy >= 0 && gy < Hd && gx >= 0 && gx < Wd) ? sp[gy * Wd + gx] : 0.f;
        }
    }
    __syncthreads();
    for (int ci = 0; ci < 16; ci++) {
        const float* wp = w1t + ci * 9 * 16;
        float pv[9];
#pragma unroll
        for (int r = 0; r < 3; r++)
#pragma unroll
            for (int cx = 0; cx < 3; cx++)
                pv[r * 3 + cx] = lds[ci][(ty + r) * 18 + tx + cx];
#pragma unroll
        for (int t = 0; t < 9; t++)
#pragma unroll
            for (int co = 0; co < 16; co++)
                acc[co] = fmaf(pv[t], wp[t * 16 + co], acc[co]);
    }
    float e = b2[0];
#pragma unroll
    for (int co = 0; co < 16; co++) e = fmaf(fmaxf(acc[co], 0.f), w2[co], e);
    float sig = 1.f / (1.f + expf(-e));
    int sp = (y0 + ty) * Wd + x0 + tx;
    ew[b * HW + sp] = sig * cm[b * HW + sp];
}

// ---------------------------------------------------------------------------
// K7/K8: 3x3 conv [64][64] via bf16 MFMA implicit GEMM, tap-split.
// 8x8 output tile x 64 co, 4 waves (wave w -> co 16w..16w+15).
// LDS: 10x10x64 bf16 halo tile, ci-octet XOR-swizzled vs (rowlin&7).
// FINAL=0: relu -> bf16 NHWC out. FINAL=1: out = x + alpha*ew*acc (fp32 NCHW).
template <int FINAL>
__global__ __launch_bounds__(256, 2)
void k_conv64m(const unsigned short* __restrict__ inh,
               const unsigned short* __restrict__ wh,
               const float* __restrict__ bias,
               unsigned short* __restrict__ outh,
               float* __restrict__ outf,
               const float* __restrict__ x,
               const float* __restrict__ ew,
               const float* __restrict__ alpha_p) {
    __shared__ unsigned short tile[100 * 64];   // 12.8 KB
    int tid = threadIdx.x;
    int x0 = blockIdx.x * 8, y0 = blockIdx.y * 8;
    int b = blockIdx.z;
    const size_t ibase = (size_t)b * HW * 64;

    for (int i = tid; i < 800; i += 256) {
        int py = i / 80;
        int r = i - py * 80;
        int px = r >> 3, cg = r & 7;
        int gy = y0 - 1 + py, gx = x0 - 1 + px;
        uint4 v = {0u, 0u, 0u, 0u};
        if (gy >= 0 && gy < Hd && gx >= 0 && gx < Wd)
            v = *(const uint4*)(inh + ibase + (size_t)(gy * Wd + gx) * 64 + cg * 8);
        int rowlin = py * 10 + px;
        int scg = cg ^ (rowlin & 7);
        *(uint4*)(tile + rowlin * 64 + scg * 8) = v;
    }

    int lane = tid & 63;
    int wv = tid >> 6;
    int l15 = lane & 15, lq = lane >> 4;
    int co_base = wv * 16;

    s8v af[9][2];
#pragma unroll
    for (int t = 0; t < 9; t++)
#pragma unroll
        for (int h = 0; h < 2; h++)
            af[t][h] = *(const s8v*)(wh + ((t * 64 + co_base + l15) * 64 + h * 32 + lq * 8));

    f4v bv = *(const f4v*)(bias + co_base + lq * 4);
    f4v acc[4];
#pragma unroll
    for (int n = 0; n < 4; n++) acc[n] = bv;

    __syncthreads();

#pragma unroll
    for (int n = 0; n < 4; n++) {
        int px = n * 16 + l15;
        int pyy = px >> 3, pxx = px & 7;
#pragma unroll
        for (int dy = 0; dy < 3; dy++) {
#pragma unroll
            for (int dx = 0; dx < 3; dx++) {
                int rowlin = (pyy + dy) * 10 + (pxx + dx);
                int sw = rowlin & 7;
                const unsigned short* tp = tile + rowlin * 64;
                s8v b0 = *(const s8v*)(tp + (lq ^ sw) * 8);
                s8v b1 = *(const s8v*)(tp + ((4 + lq) ^ sw) * 8);
                int t = dy * 3 + dx;
                acc[n] = __builtin_amdgcn_mfma_f32_16x16x32_bf16(af[t][0], b0, acc[n], 0, 0, 0);
                acc[n] = __builtin_amdgcn_mfma_f32_16x16x32_bf16(af[t][1], b1, acc[n], 0, 0, 0);
            }
        }
    }

#pragma unroll
    for (int n = 0; n < 4; n++) {
        int px = n * 16 + l15;
        int gyo = y0 + (px >> 3), gxo = x0 + (px & 7);
        int sp = gyo * Wd + gxo;
        if (FINAL) {
            float ae = alpha_p[0] * ew[b * HW + sp];
#pragma unroll
            for (int r = 0; r < 4; r++) {
                size_t o = (size_t)(b * 64 + co_base + lq * 4 + r) * HW + sp;
                outf[o] = fmaf(ae, acc[n][r], x[o]);
            }
        } else {
            alignas(8) unsigned short pk[4];
#pragma unroll
            for (int r = 0; r < 4; r++) pk[r] = f2bf(fmaxf(acc[n][r], 0.f));
            *(uint2*)(outh + ibase + (size_t)sp * 64 + co_base + lq * 4) = *(const uint2*)pk;
        }
    }
}

// ---------------------------------------------------------------------------
extern "C" void kernel_launch(void* const* d_in, const int* in_sizes, int n_in,
                              void* d_out, int out_size, void* d_ws, size_t ws_size,
                              hipStream_t stream) {
    const float* x     = (const float*)d_in[0];
    const float* wgx   = (const float*)d_in[1];
    const float* wgy   = (const float*)d_in[2];
    const float* ga_w1 = (const float*)d_in[3];
    const float* ga_b1 = (const float*)d_in[4];
    const float* ga_w2 = (const float*)d_in[5];
    const float* ga_b2 = (const float*)d_in[6];
    const float* cd_w1 = (const float*)d_in[7];
    const float* cd_b1 = (const float*)d_in[8];
    const float* cd_w2 = (const float*)d_in[9];
    const float* cd_b2 = (const float*)d_in[10];
    const float* ec_w1 = (const float*)d_in[11];
    const float* ec_b1 = (const float*)d_in[12];
    const float* ec_w2 = (const float*)d_in[13];
    const float* ec_b2 = (const float*)d_in[14];
    const float* alpha = (const float*)d_in[15];
    float* out = (float*)d_out;
    float* ws  = (float*)d_ws;

    const size_t N = 2 * 64 * HW;   // 2,097,152 floats

    // buffer plan:
    float* gx    = ws;               // N
    float* gy    = ws + N;           // N
    float* ga2   = ws + 3 * N;                    // 524288 floats
    float* cm    = ga2 + 2 * 16 * HW;             // 32768
    float* ew    = cm + 2 * HW;                   // 32768
    float* ga_w1t = ew + 2 * HW;                  // 8192
    float* ga_w2t = ga_w1t + 8192;                // 1024
    float* cd_w1t = ga_w2t + 1024;                // 2304
    unsigned short* w1h = (unsigned short*)(cd_w1t + 2304);  // 36864 shorts
    unsigned short* w2h = w1h + 36864;                       // 36864 shorts
    unsigned short* xh   = (unsigned short*)(ws + 4 * N);    // 2M shorts
    unsigned short* ee1h = xh + N;                           // 2M shorts

    k_prepxh<<<590, 256, 0, stream>>>(x, ga_w1, ga_w2, cd_w1, ec_w1, ec_w2,
                                      xh, ga_w1t, ga_w2t, cd_w1t, w1h, w2h, cm);
    k_sobcons<<<dim3(8, 8, 32), 256, 0, stream>>>(x, wgx, wgy, gx, gy, cm);
    k_ga12<<<512, 64, 0, stream>>>(gx, gy, ga_w1t, ga_b1, ga_w2t, ga_b2, ga2);
    k_cd1ew<<<dim3(8, 8, 2), 256, 0, stream>>>(ga2, cd_w1t, cd_b1, cd_w2, cd_b2, cm, ew);
    k_conv64m<0><<<dim3(16, 16, 2), 256, 0, stream>>>(xh, w1h, ec_b1, ee1h,
                                                      nullptr, nullptr, nullptr, nullptr);
    k_conv64m<1><<<dim3(16, 16, 2), 256, 0, stream>>>(ee1h, w2h, ec_b2, nullptr,
                                                      out, x, ew, alpha);
}

// Round 8
// 209.795 us; speedup vs baseline: 1.0948x; 1.0054x over previous
//
#include <hip/hip_runtime.h>
#include <math.h>

#define Hd 128
#define Wd 128
#define HW 16384      // 128*128
#define EPSc 1e-6f

typedef __attribute__((ext_vector_type(8))) short s8v;    // 8 bf16 (4 VGPRs)
typedef __attribute__((ext_vector_type(4))) float f4v;    // 4 fp32

__device__ __forceinline__ unsigned short f2bf(float f) {
    unsigned int u = __float_as_uint(f);
    unsigned int r = (u + 0x7FFFu + ((u >> 16) & 1u)) >> 16;   // RNE
    return (unsigned short)r;
}

__device__ __forceinline__ f4v fma4(float s, f4v w, f4v a) {
    a[0] = fmaf(s, w[0], a[0]);
    a[1] = fmaf(s, w[1], a[1]);
    a[2] = fmaf(s, w[2], a[2]);
    a[3] = fmaf(s, w[3], a[3]);
    return a;
}

// ---------------------------------------------------------------------------
// K0: fused weight prep + cm zero + x NCHW->NHWC bf16.
// blocks 0..127: xh transform. blocks 128..589: weight prep / cm zero.
__global__ void k_prepxh(const float* __restrict__ x,
                         const float* __restrict__ ga_w1, const float* __restrict__ ga_w2,
                         const float* __restrict__ cd_w1,
                         const float* __restrict__ ec_w1, const float* __restrict__ ec_w2,
                         unsigned short* __restrict__ xh,
                         float* __restrict__ ga_w1t, float* __restrict__ ga_w2t,
                         float* __restrict__ cd_w1t,
                         unsigned short* __restrict__ w1h, unsigned short* __restrict__ w2h,
                         float* __restrict__ cm) {
    int bid = blockIdx.x;
    if (bid < 128) {
        int p = bid * 256 + threadIdx.x;   // 0..32767
        int b = p >> 14, s = p & (HW - 1);
        const float* xp = x + (size_t)b * 64 * HW + s;
        alignas(16) unsigned short buf[64];
#pragma unroll
        for (int c = 0; c < 64; c++) buf[c] = f2bf(xp[c * HW]);
        uint4* dst = (uint4*)(xh + (size_t)p * 64);
        const uint4* src = (const uint4*)buf;
#pragma unroll
        for (int i = 0; i < 8; i++) dst[i] = src[i];
        return;
    }
    int i = (bid - 128) * 256 + threadIdx.x;
    if (i < 36864) {                               // w1h [t][co][ci]
        int t = i >> 12, co = (i >> 6) & 63, ci = i & 63;
        w1h[i] = f2bf(ec_w1[(co * 64 + ci) * 9 + t]);
    } else if (i < 73728) {                        // w2h
        int j = i - 36864;
        int t = j >> 12, co = (j >> 6) & 63, ci = j & 63;
        w2h[j] = f2bf(ec_w2[(co * 64 + ci) * 9 + t]);
    } else if (i < 81920) {                        // ga_w1t [ci128][co64]
        int j = i - 73728;
        int co = j & 63, ci = j >> 6;
        ga_w1t[j] = ga_w1[co * 128 + ci];
    } else if (i < 82944) {                        // ga_w2t [ci64][co16]
        int j = i - 81920;
        int co = j & 15, ci = j >> 4;
        ga_w2t[j] = ga_w2[co * 64 + ci];
    } else if (i < 85248) {                        // cd_w1t [ci16][tap9][co16]
        int j = i - 82944;
        int co = j & 15, r = j >> 4, t = r % 9, ci = r / 9;
        cd_w1t[j] = cd_w1[(co * 16 + ci) * 9 + t];
    } else if (i < 118016) {                       // cm zero
        cm[i - 85248] = 0.f;
    }
}

// ---------------------------------------------------------------------------
// K1: fused sobel + 5x5 weighted circular-variance + channel-mean.
// 16x16 tile, 4 channels per block. grid (8,8,32): z = b*16 + cq.
__global__ __launch_bounds__(256, 8)
void k_sobcons(const float* __restrict__ x,
               const float* __restrict__ wgx, const float* __restrict__ wgy,
               float* __restrict__ gx, float* __restrict__ gy,
               float* __restrict__ cm) {
    __shared__ float xt[484];        // 22x22 x-tile (3-halo)
    __shared__ float lm[480];        // 20 rows x stride 24
    __shared__ float ld[480];
    int tid = threadIdx.x;
    int tx = tid & 15, ty = tid >> 4;
    int x0 = blockIdx.x * 16, y0 = blockIdx.y * 16;
    int b = blockIdx.z >> 4, cb = (blockIdx.z & 15) * 4;
    float acc = 0.f;
    for (int c = 0; c < 4; c++) {
        int ch = cb + c;
        const float* xp = x + (size_t)(b * 64 + ch) * HW;
        float wx[9], wy[9];
#pragma unroll
        for (int i = 0; i < 9; i++) { wx[i] = wgx[ch * 9 + i]; wy[i] = wgy[ch * 9 + i]; }
        __syncthreads();    // previous channel's cons reads done
        for (int i = tid; i < 484; i += 256) {
            int yy = i / 22, xx = i - yy * 22;
            int gyy = y0 - 3 + yy, gxx = x0 - 3 + xx;
            xt[i] = (gyy >= 0 && gyy < Hd && gxx >= 0 && gxx < Wd) ? xp[gyy * Wd + gxx] : 0.f;
        }
        __syncthreads();
        for (int i = tid; i < 400; i += 256) {
            int yy = i / 20, xx = i - yy * 20;      // point (y0-2+yy, x0-2+xx)
            int gyy = y0 - 2 + yy, gxx = x0 - 2 + xx;
            float m = 0.f, d = 0.f, sx = 0.f, sy = 0.f;
            if (gyy >= 0 && gyy < Hd && gxx >= 0 && gxx < Wd) {
#pragma unroll
                for (int dy = 0; dy < 3; dy++)
#pragma unroll
                    for (int dx = 0; dx < 3; dx++) {
                        float v = xt[(yy + dy) * 22 + xx + dx];
                        sx = fmaf(wx[dy * 3 + dx], v, sx);
                        sy = fmaf(wy[dy * 3 + dx], v, sy);
                    }
                m = sqrtf(sx * sx + sy * sy + EPSc);
                d = atan2f(sy, sx);
            }
            lm[yy * 24 + xx] = m;
            ld[yy * 24 + xx] = d;
            if (yy >= 2 && yy < 18 && xx >= 2 && xx < 18) {
                int o = (b * 64 + ch) * HW + gyy * Wd + gxx;
                gx[o] = sx;
                gy[o] = sy;
            }
        }
        __syncthreads();
        float mv[25], dv[25];
        float sm = 0.f, sdm = 0.f;
#pragma unroll
        for (int r = 0; r < 5; r++)
#pragma unroll
            for (int cx = 0; cx < 5; cx++) {
                int idx = (ty + r) * 24 + tx + cx;
                float m = lm[idx], d = ld[idx];
                mv[r * 5 + cx] = m;
                dv[r * 5 + cx] = d;
                sm += m;
                sdm = fmaf(d, m, sdm);
            }
        float wmean = sdm / (sm + EPSc);
        float sv = 0.f;
#pragma unroll
        for (int t = 0; t < 25; t++) { float dd = dv[t] - wmean; sv = fmaf(dd * dd, mv[t], sv); }
        float wstd = sqrtf(sv / (sm + EPSc));
        acc += 1.f - tanhf(wstd);
    }
    atomicAdd(&cm[b * HW + (y0 + ty) * Wd + x0 + tx], acc * (1.f / 64.f));
}

// ---------------------------------------------------------------------------
// K2: fused ga1+ga2, one thread per pixel.
// a1 lives in 16 NAMED f4v variables (c0..c15): LLVM vectors are first-class
// SSA values -> no alloca -> no scratch. (Rounds 6/7: float a1[64] was
// demoted to scratch by SROA because indices are loop-variant pre-unroll;
// VGPR_Count 40/44, 73/51 us.)
__global__ void k_ga12(const float* __restrict__ gx, const float* __restrict__ gy,
                       const float* __restrict__ w1t, const float* __restrict__ b1,
                       const float* __restrict__ w2t, const float* __restrict__ b2,
                       float* __restrict__ ga2) {
    int p = blockIdx.x * 64 + threadIdx.x;   // 0..32767
    int b = p >> 14;
    int s = p & (HW - 1);
    const float* gxp = gx + (size_t)b * 64 * HW + s;
    const float* gyp = gy + (size_t)b * 64 * HW + s;
    const f4v* bv1 = (const f4v*)b1;
    f4v c0 = bv1[0], c1 = bv1[1], c2 = bv1[2], c3 = bv1[3];
    f4v c4 = bv1[4], c5 = bv1[5], c6 = bv1[6], c7 = bv1[7];
    f4v c8 = bv1[8], c9 = bv1[9], c10 = bv1[10], c11 = bv1[11];
    f4v c12 = bv1[12], c13 = bv1[13], c14 = bv1[14], c15 = bv1[15];

#define S1STEP(wbase) { const f4v* wv = (const f4v*)(wbase); \
    c0 = fma4(v, wv[0], c0);  c1 = fma4(v, wv[1], c1); \
    c2 = fma4(v, wv[2], c2);  c3 = fma4(v, wv[3], c3); \
    c4 = fma4(v, wv[4], c4);  c5 = fma4(v, wv[5], c5); \
    c6 = fma4(v, wv[6], c6);  c7 = fma4(v, wv[7], c7); \
    c8 = fma4(v, wv[8], c8);  c9 = fma4(v, wv[9], c9); \
    c10 = fma4(v, wv[10], c10); c11 = fma4(v, wv[11], c11); \
    c12 = fma4(v, wv[12], c12); c13 = fma4(v, wv[13], c13); \
    c14 = fma4(v, wv[14], c14); c15 = fma4(v, wv[15], c15); }

    for (int ci = 0; ci < 64; ci++) {
        float v = gxp[ci * HW];
        S1STEP(w1t + ci * 64);
    }
    for (int ci = 0; ci < 64; ci++) {
        float v = gyp[ci * HW];
        S1STEP(w1t + (64 + ci) * 64);
    }
#undef S1STEP

    const f4v* bv2 = (const f4v*)b2;
    f4v d0 = bv2[0], d1 = bv2[1], d2 = bv2[2], d3 = bv2[3];

#define S2STEP(cg, base) { const f4v* wv = (const f4v*)(w2t + (base) * 16); \
    float r0 = fmaxf(cg[0], 0.f), r1 = fmaxf(cg[1], 0.f); \
    float r2 = fmaxf(cg[2], 0.f), r3 = fmaxf(cg[3], 0.f); \
    d0 = fma4(r0, wv[0], d0);  d1 = fma4(r0, wv[1], d1); \
    d2 = fma4(r0, wv[2], d2);  d3 = fma4(r0, wv[3], d3); \
    d0 = fma4(r1, wv[4], d0);  d1 = fma4(r1, wv[5], d1); \
    d2 = fma4(r1, wv[6], d2);  d3 = fma4(r1, wv[7], d3); \
    d0 = fma4(r2, wv[8], d0);  d1 = fma4(r2, wv[9], d1); \
    d2 = fma4(r2, wv[10], d2); d3 = fma4(r2, wv[11], d3); \
    d0 = fma4(r3, wv[12], d0); d1 = fma4(r3, wv[13], d1); \
    d2 = fma4(r3, wv[14], d2); d3 = fma4(r3, wv[15], d3); }

    S2STEP(c0, 0)   S2STEP(c1, 4)   S2STEP(c2, 8)   S2STEP(c3, 12)
    S2STEP(c4, 16)  S2STEP(c5, 20)  S2STEP(c6, 24)  S2STEP(c7, 28)
    S2STEP(c8, 32)  S2STEP(c9, 36)  S2STEP(c10, 40) S2STEP(c11, 44)
    S2STEP(c12, 48) S2STEP(c13, 52) S2STEP(c14, 56) S2STEP(c15, 60)
#undef S2STEP

    float* op = ga2 + (size_t)b * 16 * HW + s;
    op[0 * HW]  = fmaxf(d0[0], 0.f); op[1 * HW]  = fmaxf(d0[1], 0.f);
    op[2 * HW]  = fmaxf(d0[2], 0.f); op[3 * HW]  = fmaxf(d0[3], 0.f);
    op[4 * HW]  = fmaxf(d1[0], 0.f); op[5 * HW]  = fmaxf(d1[1], 0.f);
    op[6 * HW]  = fmaxf(d1[2], 0.f); op[7 * HW]  = fmaxf(d1[3], 0.f);
    op[8 * HW]  = fmaxf(d2[0], 0.f); op[9 * HW]  = fmaxf(d2[1], 0.f);
    op[10 * HW] = fmaxf(d2[2], 0.f); op[11 * HW] = fmaxf(d2[3], 0.f);
    op[12 * HW] = fmaxf(d3[0], 0.f); op[13 * HW] = fmaxf(d3[1], 0.f);
    op[14 * HW] = fmaxf(d3[2], 0.f); op[15 * HW] = fmaxf(d3[3], 0.f);
}

// ---------------------------------------------------------------------------
// K5+K6 fused: 3x3 conv [16][16] + relu + 1x1 [1][16] + sigmoid, * cm -> ew
// grid (8,8,2), block 256.
__global__ __launch_bounds__(256, 4)
void k_cd1ew(const float* __restrict__ ga2, const float* __restrict__ w1t,
             const float* __restrict__ b1, const float* __restrict__ w2,
             const float* __restrict__ b2, const float* __restrict__ cm,
             float* __restrict__ ew) {
    __shared__ float lds[16][324];
    int tid = threadIdx.x;
    int tx = tid & 15, ty = tid >> 4;
    int x0 = blockIdx.x * 16, y0 = blockIdx.y * 16;
    int b = blockIdx.z;
    const float* ip = ga2 + (size_t)b * 16 * HW;
    float acc[16];
#pragma unroll
    for (int co = 0; co < 16; co++) acc[co] = b1[co];
#pragma unroll
    for (int ci = 0; ci < 16; ci++) {
        const float* sp = ip + ci * HW;
        for (int i = tid; i < 324; i += 256) {
            int yy = i / 18, xx = i - yy * 18;
            int gy = y0 - 1 + yy, gx = x0 - 1 + xx;
            lds[ci][i] = (gy >= 0 && gy < Hd && gx >= 0 && gx < Wd) ? sp[gy * Wd + gx] : 0.f;
        }
    }
    __syncthreads();
    for (int ci = 0; ci < 16; ci++) {
        const float* wp = w1t + ci * 9 * 16;
        float pv[9];
#pragma unroll
        for (int r = 0; r < 3; r++)
#pragma unroll
            for (int cx = 0; cx < 3; cx++)
                pv[r * 3 + cx] = lds[ci][(ty + r) * 18 + tx + cx];
#pragma unroll
        for (int t = 0; t < 9; t++)
#pragma unroll
            for (int co = 0; co < 16; co++)
                acc[co] = fmaf(pv[t], wp[t * 16 + co], acc[co]);
    }
    float e = b2[0];
#pragma unroll
    for (int co = 0; co < 16; co++) e = fmaf(fmaxf(acc[co], 0.f), w2[co], e);
    float sig = 1.f / (1.f + expf(-e));
    int sp = (y0 + ty) * Wd + x0 + tx;
    ew[b * HW + sp] = sig * cm[b * HW + sp];
}

// ---------------------------------------------------------------------------
// K7/K8: 3x3 conv [64][64] via bf16 MFMA implicit GEMM, tap-split.
// 8x8 output tile x 64 co, 4 waves (wave w -> co 16w..16w+15).
// LDS: 10x10x64 bf16 halo tile, ci-octet XOR-swizzled vs (rowlin&7).
// FINAL=0: relu -> bf16 NHWC out. FINAL=1: out = x + alpha*ew*acc (fp32 NCHW).
template <int FINAL>
__global__ __launch_bounds__(256, 2)
void k_conv64m(const unsigned short* __restrict__ inh,
               const unsigned short* __restrict__ wh,
               const float* __restrict__ bias,
               unsigned short* __restrict__ outh,
               float* __restrict__ outf,
               const float* __restrict__ x,
               const float* __restrict__ ew,
               const float* __restrict__ alpha_p) {
    __shared__ unsigned short tile[100 * 64];   // 12.8 KB
    int tid = threadIdx.x;
    int x0 = blockIdx.x * 8, y0 = blockIdx.y * 8;
    int b = blockIdx.z;
    const size_t ibase = (size_t)b * HW * 64;

    for (int i = tid; i < 800; i += 256) {
        int py = i / 80;
        int r = i - py * 80;
        int px = r >> 3, cg = r & 7;
        int gy = y0 - 1 + py, gx = x0 - 1 + px;
        uint4 v = {0u, 0u, 0u, 0u};
        if (gy >= 0 && gy < Hd && gx >= 0 && gx < Wd)
            v = *(const uint4*)(inh + ibase + (size_t)(gy * Wd + gx) * 64 + cg * 8);
        int rowlin = py * 10 + px;
        int scg = cg ^ (rowlin & 7);
        *(uint4*)(tile + rowlin * 64 + scg * 8) = v;
    }

    int lane = tid & 63;
    int wv = tid >> 6;
    int l15 = lane & 15, lq = lane >> 4;
    int co_base = wv * 16;

    s8v af[9][2];
#pragma unroll
    for (int t = 0; t < 9; t++)
#pragma unroll
        for (int h = 0; h < 2; h++)
            af[t][h] = *(const s8v*)(wh + ((t * 64 + co_base + l15) * 64 + h * 32 + lq * 8));

    f4v bv = *(const f4v*)(bias + co_base + lq * 4);
    f4v acc[4];
#pragma unroll
    for (int n = 0; n < 4; n++) acc[n] = bv;

    __syncthreads();

#pragma unroll
    for (int n = 0; n < 4; n++) {
        int px = n * 16 + l15;
        int pyy = px >> 3, pxx = px & 7;
#pragma unroll
        for (int dy = 0; dy < 3; dy++) {
#pragma unroll
            for (int dx = 0; dx < 3; dx++) {
                int rowlin = (pyy + dy) * 10 + (pxx + dx);
                int sw = rowlin & 7;
                const unsigned short* tp = tile + rowlin * 64;
                s8v b0 = *(const s8v*)(tp + (lq ^ sw) * 8);
                s8v b1 = *(const s8v*)(tp + ((4 + lq) ^ sw) * 8);
                int t = dy * 3 + dx;
                acc[n] = __builtin_amdgcn_mfma_f32_16x16x32_bf16(af[t][0], b0, acc[n], 0, 0, 0);
                acc[n] = __builtin_amdgcn_mfma_f32_16x16x32_bf16(af[t][1], b1, acc[n], 0, 0, 0);
            }
        }
    }

#pragma unroll
    for (int n = 0; n < 4; n++) {
        int px = n * 16 + l15;
        int gyo = y0 + (px >> 3), gxo = x0 + (px & 7);
        int sp = gyo * Wd + gxo;
        if (FINAL) {
            float ae = alpha_p[0] * ew[b * HW + sp];
#pragma unroll
            for (int r = 0; r < 4; r++) {
                size_t o = (size_t)(b * 64 + co_base + lq * 4 + r) * HW + sp;
                outf[o] = fmaf(ae, acc[n][r], x[o]);
            }
        } else {
            alignas(8) unsigned short pk[4];
#pragma unroll
            for (int r = 0; r < 4; r++) pk[r] = f2bf(fmaxf(acc[n][r], 0.f));
            *(uint2*)(outh + ibase + (size_t)sp * 64 + co_base + lq * 4) = *(const uint2*)pk;
        }
    }
}

// ---------------------------------------------------------------------------
extern "C" void kernel_launch(void* const* d_in, const int* in_sizes, int n_in,
                              void* d_out, int out_size, void* d_ws, size_t ws_size,
                              hipStream_t stream) {
    const float* x     = (const float*)d_in[0];
    const float* wgx   = (const float*)d_in[1];
    const float* wgy   = (const float*)d_in[2];
    const float* ga_w1 = (const float*)d_in[3];
    const float* ga_b1 = (const float*)d_in[4];
    const float* ga_w2 = (const float*)d_in[5];
    const float* ga_b2 = (const float*)d_in[6];
    const float* cd_w1 = (const float*)d_in[7];
    const float* cd_b1 = (const float*)d_in[8];
    const float* cd_w2 = (const float*)d_in[9];
    const float* cd_b2 = (const float*)d_in[10];
    const float* ec_w1 = (const float*)d_in[11];
    const float* ec_b1 = (const float*)d_in[12];
    const float* ec_w2 = (const float*)d_in[13];
    const float* ec_b2 = (const float*)d_in[14];
    const float* alpha = (const float*)d_in[15];
    float* out = (float*)d_out;
    float* ws  = (float*)d_ws;

    const size_t N = 2 * 64 * HW;   // 2,097,152 floats

    // buffer plan:
    float* gx    = ws;               // N
    float* gy    = ws + N;           // N
    float* ga2   = ws + 3 * N;                    // 524288 floats
    float* cm    = ga2 + 2 * 16 * HW;             // 32768
    float* ew    = cm + 2 * HW;                   // 32768
    float* ga_w1t = ew + 2 * HW;                  // 8192
    float* ga_w2t = ga_w1t + 8192;                // 1024
    float* cd_w1t = ga_w2t + 1024;                // 2304
    unsigned short* w1h = (unsigned short*)(cd_w1t + 2304);  // 36864 shorts
    unsigned short* w2h = w1h + 36864;                       // 36864 shorts
    unsigned short* xh   = (unsigned short*)(ws + 4 * N);    // 2M shorts
    unsigned short* ee1h = xh + N;                           // 2M shorts

    k_prepxh<<<590, 256, 0, stream>>>(x, ga_w1, ga_w2, cd_w1, ec_w1, ec_w2,
                                      xh, ga_w1t, ga_w2t, cd_w1t, w1h, w2h, cm);
    k_sobcons<<<dim3(8, 8, 32), 256, 0, stream>>>(x, wgx, wgy, gx, gy, cm);
    k_ga12<<<512, 64, 0, stream>>>(gx, gy, ga_w1t, ga_b1, ga_w2t, ga_b2, ga2);
    k_cd1ew<<<dim3(8, 8, 2), 256, 0, stream>>>(ga2, cd_w1t, cd_b1, cd_w2, cd_b2, cm, ew);
    k_conv64m<0><<<dim3(16, 16, 2), 256, 0, stream>>>(xh, w1h, ec_b1, ee1h,
                                                      nullptr, nullptr, nullptr, nullptr);
    k_conv64m<1><<<dim3(16, 16, 2), 256, 0, stream>>>(ee1h, w2h, ec_b2, nullptr,
                                                      out, x, ew, alpha);
}

// Round 9
// 190.820 us; speedup vs baseline: 1.2037x; 1.0994x over previous
//
#include <hip/hip_runtime.h>
#include <math.h>

#define Hd 128
#define Wd 128
#define HW 16384      // 128*128
#define EPSc 1e-6f

typedef __attribute__((ext_vector_type(8))) short s8v;    // 8 bf16 (4 VGPRs)
typedef __attribute__((ext_vector_type(4))) float f4v;    // 4 fp32

__device__ __forceinline__ unsigned short f2bf(float f) {
    unsigned int u = __float_as_uint(f);
    unsigned int r = (u + 0x7FFFu + ((u >> 16) & 1u)) >> 16;   // RNE
    return (unsigned short)r;
}

// ---------------------------------------------------------------------------
// K0: fused weight prep + cm zero + x NCHW->NHWC bf16.
// blocks 0..127: xh transform. blocks 128..589: weight prep / cm zero.
// (Measured across r5-r8: fusing prep+xh saves ~9 us vs separate dispatches.)
__global__ void k_prepxh(const float* __restrict__ x,
                         const float* __restrict__ ga_w1, const float* __restrict__ ga_w2,
                         const float* __restrict__ cd_w1,
                         const float* __restrict__ ec_w1, const float* __restrict__ ec_w2,
                         unsigned short* __restrict__ xh,
                         float* __restrict__ ga_w1t, float* __restrict__ ga_w2t,
                         float* __restrict__ cd_w1t,
                         unsigned short* __restrict__ w1h, unsigned short* __restrict__ w2h,
                         float* __restrict__ cm) {
    int bid = blockIdx.x;
    if (bid < 128) {
        int p = bid * 256 + threadIdx.x;   // 0..32767
        int b = p >> 14, s = p & (HW - 1);
        const float* xp = x + (size_t)b * 64 * HW + s;
        alignas(16) unsigned short buf[64];
#pragma unroll
        for (int c = 0; c < 64; c++) buf[c] = f2bf(xp[c * HW]);
        uint4* dst = (uint4*)(xh + (size_t)p * 64);
        const uint4* src = (const uint4*)buf;
#pragma unroll
        for (int i = 0; i < 8; i++) dst[i] = src[i];
        return;
    }
    int i = (bid - 128) * 256 + threadIdx.x;
    if (i < 36864) {                               // w1h [t][co][ci]
        int t = i >> 12, co = (i >> 6) & 63, ci = i & 63;
        w1h[i] = f2bf(ec_w1[(co * 64 + ci) * 9 + t]);
    } else if (i < 73728) {                        // w2h
        int j = i - 36864;
        int t = j >> 12, co = (j >> 6) & 63, ci = j & 63;
        w2h[j] = f2bf(ec_w2[(co * 64 + ci) * 9 + t]);
    } else if (i < 81920) {                        // ga_w1t [ci128][co64]
        int j = i - 73728;
        int co = j & 63, ci = j >> 6;
        ga_w1t[j] = ga_w1[co * 128 + ci];
    } else if (i < 82944) {                        // ga_w2t [ci64][co16]
        int j = i - 81920;
        int co = j & 15, ci = j >> 4;
        ga_w2t[j] = ga_w2[co * 64 + ci];
    } else if (i < 85248) {                        // cd_w1t [ci16][tap9][co16]
        int j = i - 82944;
        int co = j & 15, r = j >> 4, t = r % 9, ci = r / 9;
        cd_w1t[j] = cd_w1[(co * 16 + ci) * 9 + t];
    } else if (i < 118016) {                       // cm zero
        cm[i - 85248] = 0.f;
    }
}

// ---------------------------------------------------------------------------
// K1: fused sobel + 5x5 weighted circular-variance + channel-mean.
// 16x16 tile, 4 channels per block. grid (8,8,32): z = b*16 + cq.
// 8 blocks/CU (32 waves); lm/ld stride 24 (2-way banks = free).
__global__ __launch_bounds__(256, 8)
void k_sobcons(const float* __restrict__ x,
               const float* __restrict__ wgx, const float* __restrict__ wgy,
               float* __restrict__ gx, float* __restrict__ gy,
               float* __restrict__ cm) {
    __shared__ float xt[484];        // 22x22 x-tile (3-halo)
    __shared__ float lm[480];        // 20 rows x stride 24
    __shared__ float ld[480];
    int tid = threadIdx.x;
    int tx = tid & 15, ty = tid >> 4;
    int x0 = blockIdx.x * 16, y0 = blockIdx.y * 16;
    int b = blockIdx.z >> 4, cb = (blockIdx.z & 15) * 4;
    float acc = 0.f;
    for (int c = 0; c < 4; c++) {
        int ch = cb + c;
        const float* xp = x + (size_t)(b * 64 + ch) * HW;
        float wx[9], wy[9];
#pragma unroll
        for (int i = 0; i < 9; i++) { wx[i] = wgx[ch * 9 + i]; wy[i] = wgy[ch * 9 + i]; }
        __syncthreads();    // previous channel's cons reads done
        for (int i = tid; i < 484; i += 256) {
            int yy = i / 22, xx = i - yy * 22;
            int gyy = y0 - 3 + yy, gxx = x0 - 3 + xx;
            xt[i] = (gyy >= 0 && gyy < Hd && gxx >= 0 && gxx < Wd) ? xp[gyy * Wd + gxx] : 0.f;
        }
        __syncthreads();
        for (int i = tid; i < 400; i += 256) {
            int yy = i / 20, xx = i - yy * 20;      // point (y0-2+yy, x0-2+xx)
            int gyy = y0 - 2 + yy, gxx = x0 - 2 + xx;
            float m = 0.f, d = 0.f, sx = 0.f, sy = 0.f;
            if (gyy >= 0 && gyy < Hd && gxx >= 0 && gxx < Wd) {
#pragma unroll
                for (int dy = 0; dy < 3; dy++)
#pragma unroll
                    for (int dx = 0; dx < 3; dx++) {
                        float v = xt[(yy + dy) * 22 + xx + dx];
                        sx = fmaf(wx[dy * 3 + dx], v, sx);
                        sy = fmaf(wy[dy * 3 + dx], v, sy);
                    }
                m = sqrtf(sx * sx + sy * sy + EPSc);
                d = atan2f(sy, sx);
            }
            lm[yy * 24 + xx] = m;
            ld[yy * 24 + xx] = d;
            if (yy >= 2 && yy < 18 && xx >= 2 && xx < 18) {
                int o = (b * 64 + ch) * HW + gyy * Wd + gxx;
                gx[o] = sx;
                gy[o] = sy;
            }
        }
        __syncthreads();
        float mv[25], dv[25];
        float sm = 0.f, sdm = 0.f;
#pragma unroll
        for (int r = 0; r < 5; r++)
#pragma unroll
            for (int cx = 0; cx < 5; cx++) {
                int idx = (ty + r) * 24 + tx + cx;
                float m = lm[idx], d = ld[idx];
                mv[r * 5 + cx] = m;
                dv[r * 5 + cx] = d;
                sm += m;
                sdm = fmaf(d, m, sdm);
            }
        float wmean = sdm / (sm + EPSc);
        float sv = 0.f;
#pragma unroll
        for (int t = 0; t < 25; t++) { float dd = dv[t] - wmean; sv = fmaf(dd * dd, mv[t], sv); }
        float wstd = sqrtf(sv / (sm + EPSc));
        acc += 1.f - tanhf(wstd);
    }
    atomicAdd(&cm[b * HW + (y0 + ty) * Wd + x0 + tx], acc * (1.f / 64.f));
}

// ---------------------------------------------------------------------------
// K2: 1x1 conv [64 out][128 in] + relu.  grid (128,4), block 256.
// (Round-5 known-good config. The in-thread ga1+ga2 fusion (r6-r8) loses:
// compiler refuses to keep a 64-wide accumulator in VGPRs, 50-73 us.)
__global__ void k_ga1(const float* __restrict__ gx, const float* __restrict__ gy,
                      const float* __restrict__ w1t, const float* __restrict__ b1,
                      float* __restrict__ ga1) {
    int p = blockIdx.x * 256 + threadIdx.x;   // 0..32767
    int cb = blockIdx.y * 16;
    int b = p >> 14;
    int s = p & (HW - 1);
    const float* gxp = gx + (size_t)b * 64 * HW + s;
    const float* gyp = gy + (size_t)b * 64 * HW + s;
    float acc[16];
#pragma unroll
    for (int co = 0; co < 16; co++) acc[co] = b1[cb + co];
    for (int ci = 0; ci < 64; ci++) {
        float v = gxp[ci * HW];
        const float* wp = w1t + ci * 64 + cb;
#pragma unroll
        for (int co = 0; co < 16; co++) acc[co] = fmaf(v, wp[co], acc[co]);
    }
    for (int ci = 0; ci < 64; ci++) {
        float v = gyp[ci * HW];
        const float* wp = w1t + (64 + ci) * 64 + cb;
#pragma unroll
        for (int co = 0; co < 16; co++) acc[co] = fmaf(v, wp[co], acc[co]);
    }
    float* op = ga1 + (size_t)b * 64 * HW + s;
#pragma unroll
    for (int co = 0; co < 16; co++) op[(cb + co) * HW] = fmaxf(acc[co], 0.f);
}

// ---------------------------------------------------------------------------
// K2b: 1x1 conv [16 out][64 in] + relu. grid 128, block 256.
__global__ void k_ga2(const float* __restrict__ ga1, const float* __restrict__ w2t,
                      const float* __restrict__ b2, float* __restrict__ ga2) {
    int p = blockIdx.x * 256 + threadIdx.x;
    int b = p >> 14;
    int s = p & (HW - 1);
    const float* ip = ga1 + (size_t)b * 64 * HW + s;
    float acc[16];
#pragma unroll
    for (int co = 0; co < 16; co++) acc[co] = b2[co];
    for (int ci = 0; ci < 64; ci++) {
        float v = ip[ci * HW];
        const float* wp = w2t + ci * 16;
#pragma unroll
        for (int co = 0; co < 16; co++) acc[co] = fmaf(v, wp[co], acc[co]);
    }
    float* op = ga2 + (size_t)b * 16 * HW + s;
#pragma unroll
    for (int co = 0; co < 16; co++) op[co * HW] = fmaxf(acc[co], 0.f);
}

// ---------------------------------------------------------------------------
// K5+K6 fused: 3x3 conv [16][16] + relu + 1x1 [1][16] + sigmoid, * cm -> ew
// grid (8,8,2), block 256.
__global__ __launch_bounds__(256, 4)
void k_cd1ew(const float* __restrict__ ga2, const float* __restrict__ w1t,
             const float* __restrict__ b1, const float* __restrict__ w2,
             const float* __restrict__ b2, const float* __restrict__ cm,
             float* __restrict__ ew) {
    __shared__ float lds[16][324];
    int tid = threadIdx.x;
    int tx = tid & 15, ty = tid >> 4;
    int x0 = blockIdx.x * 16, y0 = blockIdx.y * 16;
    int b = blockIdx.z;
    const float* ip = ga2 + (size_t)b * 16 * HW;
    float acc[16];
#pragma unroll
    for (int co = 0; co < 16; co++) acc[co] = b1[co];
#pragma unroll
    for (int ci = 0; ci < 16; ci++) {
        const float* sp = ip + ci * HW;
        for (int i = tid; i < 324; i += 256) {
            int yy = i / 18, xx = i - yy * 18;
            int gy = y0 - 1 + yy, gx = x0 - 1 + xx;
            lds[ci][i] = (gy >= 0 && gy < Hd && gx >= 0 && gx < Wd) ? sp[gy * Wd + gx] : 0.f;
        }
    }
    __syncthreads();
    for (int ci = 0; ci < 16; ci++) {
        const float* wp = w1t + ci * 9 * 16;
        float pv[9];
#pragma unroll
        for (int r = 0; r < 3; r++)
#pragma unroll
            for (int cx = 0; cx < 3; cx++)
                pv[r * 3 + cx] = lds[ci][(ty + r) * 18 + tx + cx];
#pragma unroll
        for (int t = 0; t < 9; t++)
#pragma unroll
            for (int co = 0; co < 16; co++)
                acc[co] = fmaf(pv[t], wp[t * 16 + co], acc[co]);
    }
    float e = b2[0];
#pragma unroll
    for (int co = 0; co < 16; co++) e = fmaf(fmaxf(acc[co], 0.f), w2[co], e);
    float sig = 1.f / (1.f + expf(-e));
    int sp = (y0 + ty) * Wd + x0 + tx;
    ew[b * HW + sp] = sig * cm[b * HW + sp];
}

// ---------------------------------------------------------------------------
// K7/K8: 3x3 conv [64][64] via bf16 MFMA implicit GEMM, tap-split.
// 8x8 output tile x 64 co, 4 waves (wave w -> co 16w..16w+15).
// LDS: 10x10x64 bf16 halo tile, ci-octet XOR-swizzled vs (rowlin&7).
// FINAL=0: relu -> bf16 NHWC out. FINAL=1: out = x + alpha*ew*acc (fp32 NCHW).
template <int FINAL>
__global__ __launch_bounds__(256, 2)
void k_conv64m(const unsigned short* __restrict__ inh,
               const unsigned short* __restrict__ wh,
               const float* __restrict__ bias,
               unsigned short* __restrict__ outh,
               float* __restrict__ outf,
               const float* __restrict__ x,
               const float* __restrict__ ew,
               const float* __restrict__ alpha_p) {
    __shared__ unsigned short tile[100 * 64];   // 12.8 KB
    int tid = threadIdx.x;
    int x0 = blockIdx.x * 8, y0 = blockIdx.y * 8;
    int b = blockIdx.z;
    const size_t ibase = (size_t)b * HW * 64;

    for (int i = tid; i < 800; i += 256) {
        int py = i / 80;
        int r = i - py * 80;
        int px = r >> 3, cg = r & 7;
        int gy = y0 - 1 + py, gx = x0 - 1 + px;
        uint4 v = {0u, 0u, 0u, 0u};
        if (gy >= 0 && gy < Hd && gx >= 0 && gx < Wd)
            v = *(const uint4*)(inh + ibase + (size_t)(gy * Wd + gx) * 64 + cg * 8);
        int rowlin = py * 10 + px;
        int scg = cg ^ (rowlin & 7);
        *(uint4*)(tile + rowlin * 64 + scg * 8) = v;
    }

    int lane = tid & 63;
    int wv = tid >> 6;
    int l15 = lane & 15, lq = lane >> 4;
    int co_base = wv * 16;

    s8v af[9][2];
#pragma unroll
    for (int t = 0; t < 9; t++)
#pragma unroll
        for (int h = 0; h < 2; h++)
            af[t][h] = *(const s8v*)(wh + ((t * 64 + co_base + l15) * 64 + h * 32 + lq * 8));

    f4v bv = *(const f4v*)(bias + co_base + lq * 4);
    f4v acc[4];
#pragma unroll
    for (int n = 0; n < 4; n++) acc[n] = bv;

    __syncthreads();

#pragma unroll
    for (int n = 0; n < 4; n++) {
        int px = n * 16 + l15;
        int pyy = px >> 3, pxx = px & 7;
#pragma unroll
        for (int dy = 0; dy < 3; dy++) {
#pragma unroll
            for (int dx = 0; dx < 3; dx++) {
                int rowlin = (pyy + dy) * 10 + (pxx + dx);
                int sw = rowlin & 7;
                const unsigned short* tp = tile + rowlin * 64;
                s8v b0 = *(const s8v*)(tp + (lq ^ sw) * 8);
                s8v b1 = *(const s8v*)(tp + ((4 + lq) ^ sw) * 8);
                int t = dy * 3 + dx;
                acc[n] = __builtin_amdgcn_mfma_f32_16x16x32_bf16(af[t][0], b0, acc[n], 0, 0, 0);
                acc[n] = __builtin_amdgcn_mfma_f32_16x16x32_bf16(af[t][1], b1, acc[n], 0, 0, 0);
            }
        }
    }

#pragma unroll
    for (int n = 0; n < 4; n++) {
        int px = n * 16 + l15;
        int gyo = y0 + (px >> 3), gxo = x0 + (px & 7);
        int sp = gyo * Wd + gxo;
        if (FINAL) {
            float ae = alpha_p[0] * ew[b * HW + sp];
#pragma unroll
            for (int r = 0; r < 4; r++) {
                size_t o = (size_t)(b * 64 + co_base + lq * 4 + r) * HW + sp;
                outf[o] = fmaf(ae, acc[n][r], x[o]);
            }
        } else {
            alignas(8) unsigned short pk[4];
#pragma unroll
            for (int r = 0; r < 4; r++) pk[r] = f2bf(fmaxf(acc[n][r], 0.f));
            *(uint2*)(outh + ibase + (size_t)sp * 64 + co_base + lq * 4) = *(const uint2*)pk;
        }
    }
}

// ---------------------------------------------------------------------------
extern "C" void kernel_launch(void* const* d_in, const int* in_sizes, int n_in,
                              void* d_out, int out_size, void* d_ws, size_t ws_size,
                              hipStream_t stream) {
    const float* x     = (const float*)d_in[0];
    const float* wgx   = (const float*)d_in[1];
    const float* wgy   = (const float*)d_in[2];
    const float* ga_w1 = (const float*)d_in[3];
    const float* ga_b1 = (const float*)d_in[4];
    const float* ga_w2 = (const float*)d_in[5];
    const float* ga_b2 = (const float*)d_in[6];
    const float* cd_w1 = (const float*)d_in[7];
    const float* cd_b1 = (const float*)d_in[8];
    const float* cd_w2 = (const float*)d_in[9];
    const float* cd_b2 = (const float*)d_in[10];
    const float* ec_w1 = (const float*)d_in[11];
    const float* ec_b1 = (const float*)d_in[12];
    const float* ec_w2 = (const float*)d_in[13];
    const float* ec_b2 = (const float*)d_in[14];
    const float* alpha = (const float*)d_in[15];
    float* out = (float*)d_out;
    float* ws  = (float*)d_ws;

    const size_t N = 2 * 64 * HW;   // 2,097,152 floats

    // buffer plan:
    float* gx    = ws;               // N
    float* gy    = ws + N;           // N
    float* ga1   = ws + 2 * N;       // N
    float* ga2   = ws + 3 * N;                    // 524288 floats
    float* cm    = ga2 + 2 * 16 * HW;             // 32768
    float* ew    = cm + 2 * HW;                   // 32768
    float* ga_w1t = ew + 2 * HW;                  // 8192
    float* ga_w2t = ga_w1t + 8192;                // 1024
    float* cd_w1t = ga_w2t + 1024;                // 2304
    unsigned short* w1h = (unsigned short*)(cd_w1t + 2304);  // 36864 shorts
    unsigned short* w2h = w1h + 36864;                       // 36864 shorts
    unsigned short* xh   = (unsigned short*)(ws + 4 * N);    // 2M shorts
    unsigned short* ee1h = xh + N;                           // 2M shorts

    k_prepxh<<<590, 256, 0, stream>>>(x, ga_w1, ga_w2, cd_w1, ec_w1, ec_w2,
                                      xh, ga_w1t, ga_w2t, cd_w1t, w1h, w2h, cm);
    k_sobcons<<<dim3(8, 8, 32), 256, 0, stream>>>(x, wgx, wgy, gx, gy, cm);
    k_ga1<<<dim3(128, 4), 256, 0, stream>>>(gx, gy, ga_w1t, ga_b1, ga1);
    k_ga2<<<128, 256, 0, stream>>>(ga1, ga_w2t, ga_b2, ga2);
    k_cd1ew<<<dim3(8, 8, 2), 256, 0, stream>>>(ga2, cd_w1t, cd_b1, cd_w2, cd_b2, cm, ew);
    k_conv64m<0><<<dim3(16, 16, 2), 256, 0, stream>>>(xh, w1h, ec_b1, ee1h,
                                                      nullptr, nullptr, nullptr, nullptr);
    k_conv64m<1><<<dim3(16, 16, 2), 256, 0, stream>>>(ee1h, w2h, ec_b2, nullptr,
                                                      out, x, ew, alpha);
}

// Round 10
// 167.093 us; speedup vs baseline: 1.3746x; 1.1420x over previous
//
#include <hip/hip_runtime.h>
#include <math.h>

#define Hd 128
#define Wd 128
#define HW 16384      // 128*128
#define EPSc 1e-6f

typedef __attribute__((ext_vector_type(8))) short s8v;    // 8 bf16 (4 VGPRs)
typedef __attribute__((ext_vector_type(4))) float f4v;    // 4 fp32

__device__ __forceinline__ unsigned short f2bf(float f) {
    unsigned int u = __float_as_uint(f);
    unsigned int r = (u + 0x7FFFu + ((u >> 16) & 1u)) >> 16;   // RNE
    return (unsigned short)r;
}

// ---------------------------------------------------------------------------
// K0: fused weight prep + cm zero + x NCHW->NHWC bf16.
// blocks 0..127: xh transform. blocks 128..589: weight prep / cm zero.
__global__ void k_prepxh(const float* __restrict__ x,
                         const float* __restrict__ ga_w1, const float* __restrict__ ga_w2,
                         const float* __restrict__ cd_w1,
                         const float* __restrict__ ec_w1, const float* __restrict__ ec_w2,
                         unsigned short* __restrict__ xh,
                         unsigned short* __restrict__ w1m, unsigned short* __restrict__ w2m,
                         float* __restrict__ cd_w1t,
                         unsigned short* __restrict__ w1h, unsigned short* __restrict__ w2h,
                         float* __restrict__ cm) {
    int bid = blockIdx.x;
    if (bid < 128) {
        int p = bid * 256 + threadIdx.x;   // 0..32767
        int b = p >> 14, s = p & (HW - 1);
        const float* xp = x + (size_t)b * 64 * HW + s;
        alignas(16) unsigned short buf[64];
#pragma unroll
        for (int c = 0; c < 64; c++) buf[c] = f2bf(xp[c * HW]);
        uint4* dst = (uint4*)(xh + (size_t)p * 64);
        const uint4* src = (const uint4*)buf;
#pragma unroll
        for (int i = 0; i < 8; i++) dst[i] = src[i];
        return;
    }
    int i = (bid - 128) * 256 + threadIdx.x;
    if (i < 36864) {                               // w1h [t][co][ci] bf16 (ec_w1)
        int t = i >> 12, co = (i >> 6) & 63, ci = i & 63;
        w1h[i] = f2bf(ec_w1[(co * 64 + ci) * 9 + t]);
    } else if (i < 73728) {                        // w2h (ec_w2)
        int j = i - 36864;
        int t = j >> 12, co = (j >> 6) & 63, ci = j & 63;
        w2h[j] = f2bf(ec_w2[(co * 64 + ci) * 9 + t]);
    } else if (i < 81920) {                        // w1m [co64][K128] bf16 = ga_w1 cast
        int j = i - 73728;
        w1m[j] = f2bf(ga_w1[j]);
    } else if (i < 82944) {                        // w2m [co16][ci64] bf16 = ga_w2 cast
        int j = i - 81920;
        w2m[j] = f2bf(ga_w2[j]);
    } else if (i < 85248) {                        // cd_w1t [ci16][tap9][co16] fp32
        int j = i - 82944;
        int co = j & 15, r = j >> 4, t = r % 9, ci = r / 9;
        cd_w1t[j] = cd_w1[(co * 16 + ci) * 9 + t];
    } else if (i < 118016) {                       // cm zero
        cm[i - 85248] = 0.f;
    }
}

// ---------------------------------------------------------------------------
// K1: fused sobel + 5x5 weighted circular-variance + channel-mean.
// 16x16 tile, 4 channels per block. grid (8,8,32): z = b*16 + cq.
// Emits gx/gy as bf16 NHWC [p][128] (gx->ch, gy->64+ch) for the MFMA ga-GEMM.
__global__ __launch_bounds__(256, 8)
void k_sobcons(const float* __restrict__ x,
               const float* __restrict__ wgx, const float* __restrict__ wgy,
               unsigned short* __restrict__ gxgyh,
               float* __restrict__ cm) {
    __shared__ float xt[484];        // 22x22 x-tile (3-halo)
    __shared__ float lm[480];        // 20 rows x stride 24
    __shared__ float ld[480];
    int tid = threadIdx.x;
    int tx = tid & 15, ty = tid >> 4;
    int x0 = blockIdx.x * 16, y0 = blockIdx.y * 16;
    int b = blockIdx.z >> 4, cb = (blockIdx.z & 15) * 4;
    float acc = 0.f;
    for (int c = 0; c < 4; c++) {
        int ch = cb + c;
        const float* xp = x + (size_t)(b * 64 + ch) * HW;
        float wx[9], wy[9];
#pragma unroll
        for (int i = 0; i < 9; i++) { wx[i] = wgx[ch * 9 + i]; wy[i] = wgy[ch * 9 + i]; }
        __syncthreads();    // previous channel's cons reads done
        for (int i = tid; i < 484; i += 256) {
            int yy = i / 22, xx = i - yy * 22;
            int gyy = y0 - 3 + yy, gxx = x0 - 3 + xx;
            xt[i] = (gyy >= 0 && gyy < Hd && gxx >= 0 && gxx < Wd) ? xp[gyy * Wd + gxx] : 0.f;
        }
        __syncthreads();
        for (int i = tid; i < 400; i += 256) {
            int yy = i / 20, xx = i - yy * 20;      // point (y0-2+yy, x0-2+xx)
            int gyy = y0 - 2 + yy, gxx = x0 - 2 + xx;
            float m = 0.f, d = 0.f, sx = 0.f, sy = 0.f;
            if (gyy >= 0 && gyy < Hd && gxx >= 0 && gxx < Wd) {
#pragma unroll
                for (int dy = 0; dy < 3; dy++)
#pragma unroll
                    for (int dx = 0; dx < 3; dx++) {
                        float v = xt[(yy + dy) * 22 + xx + dx];
                        sx = fmaf(wx[dy * 3 + dx], v, sx);
                        sy = fmaf(wy[dy * 3 + dx], v, sy);
                    }
                m = sqrtf(sx * sx + sy * sy + EPSc);
                d = atan2f(sy, sx);
            }
            lm[yy * 24 + xx] = m;
            ld[yy * 24 + xx] = d;
            if (yy >= 2 && yy < 18 && xx >= 2 && xx < 18) {
                size_t pb = ((size_t)b * HW + gyy * Wd + gxx) * 128;
                gxgyh[pb + ch] = f2bf(sx);
                gxgyh[pb + 64 + ch] = f2bf(sy);
            }
        }
        __syncthreads();
        float mv[25], dv[25];
        float sm = 0.f, sdm = 0.f;
#pragma unroll
        for (int r = 0; r < 5; r++)
#pragma unroll
            for (int cx = 0; cx < 5; cx++) {
                int idx = (ty + r) * 24 + tx + cx;
                float m = lm[idx], d = ld[idx];
                mv[r * 5 + cx] = m;
                dv[r * 5 + cx] = d;
                sm += m;
                sdm = fmaf(d, m, sdm);
            }
        float wmean = sdm / (sm + EPSc);
        float sv = 0.f;
#pragma unroll
        for (int t = 0; t < 25; t++) { float dd = dv[t] - wmean; sv = fmaf(dd * dd, mv[t], sv); }
        float wstd = sqrtf(sv / (sm + EPSc));
        acc += 1.f - tanhf(wstd);
    }
    atomicAdd(&cm[b * HW + (y0 + ty) * Wd + x0 + tx], acc * (1.f / 64.f));
}

// ---------------------------------------------------------------------------
// K2: ga1+ga2 fused via bf16 MFMA (sidesteps the r6-r8 VALU register cliff:
// accumulators live in AGPRs). Per block: 64 pixels, 4 waves.
// Stage 1: D1[64co x 64px] = w1m[64x128] . A[128 x 64px], relu -> P (LDS bf16).
// Stage 2: D2[16co x 64px] = w2m[16x64] . P, relu -> ga2 fp32 NCHW.
// LDS XOR-octet swizzles keep all ds accesses <=2-way (free).
__global__ __launch_bounds__(256, 2)
void k_gam(const unsigned short* __restrict__ gxgyh,
           const unsigned short* __restrict__ w1m, const float* __restrict__ b1,
           const unsigned short* __restrict__ w2m, const float* __restrict__ b2,
           float* __restrict__ ga2) {
    __shared__ unsigned short la[64 * 128];   // 16 KB A-tile
    __shared__ unsigned short lp[64 * 64];    // 8 KB P-tile
    int tid = threadIdx.x;
    int p0 = blockIdx.x * 64;                 // 64 consecutive pixels
    int b = p0 >> 14;
    int s0 = p0 & (HW - 1);

    // stage A: 64px x 128ch bf16, swizzle ch-octet cg ^ (px&15)
    const unsigned short* src = gxgyh + (size_t)p0 * 128;
    for (int i = tid; i < 1024; i += 256) {
        int px = i >> 4, cg = i & 15;
        uint4 v = *(const uint4*)(src + px * 128 + cg * 8);
        *(uint4*)(la + px * 128 + ((cg ^ (px & 15)) * 8)) = v;
    }

    int lane = tid & 63, wv = tid >> 6;
    int l15 = lane & 15, lq = lane >> 4;
    int co_base = wv * 16;

    s8v af[4];
#pragma unroll
    for (int h = 0; h < 4; h++)
        af[h] = *(const s8v*)(w1m + (co_base + l15) * 128 + h * 32 + lq * 8);
    f4v bv = *(const f4v*)(b1 + co_base + lq * 4);
    f4v acc[4];
#pragma unroll
    for (int n = 0; n < 4; n++) acc[n] = bv;

    __syncthreads();

#pragma unroll
    for (int n = 0; n < 4; n++) {
        const unsigned short* tp = la + (n * 16 + l15) * 128;
#pragma unroll
        for (int h = 0; h < 4; h++) {
            s8v bb = *(const s8v*)(tp + (((h * 4 + lq) ^ l15) * 8));
            acc[n] = __builtin_amdgcn_mfma_f32_16x16x32_bf16(af[h], bb, acc[n], 0, 0, 0);
        }
    }

    // write P = relu(D1) as bf16 [px][64co], octet og ^ (px&7)
    int co = co_base + lq * 4;
    int og = co >> 3;
#pragma unroll
    for (int n = 0; n < 4; n++) {
        int px = n * 16 + l15;
        alignas(8) unsigned short pk[4];
#pragma unroll
        for (int r = 0; r < 4; r++) pk[r] = f2bf(fmaxf(acc[n][r], 0.f));
        *(uint2*)(lp + px * 64 + ((og ^ (px & 7)) * 8) + (co & 7)) = *(const uint2*)pk;
    }
    __syncthreads();

    // stage 2: each wave handles its 16-px group
    s8v af2[2];
#pragma unroll
    for (int h = 0; h < 2; h++)
        af2[h] = *(const s8v*)(w2m + l15 * 64 + h * 32 + lq * 8);
    f4v acc2 = *(const f4v*)(b2 + lq * 4);
    int px2 = wv * 16 + l15;
    const unsigned short* tp2 = lp + px2 * 64;
#pragma unroll
    for (int h = 0; h < 2; h++) {
        s8v bb = *(const s8v*)(tp2 + (((h * 4 + lq) ^ (px2 & 7)) * 8));
        acc2 = __builtin_amdgcn_mfma_f32_16x16x32_bf16(af2[h], bb, acc2, 0, 0, 0);
    }
    float* op = ga2 + (size_t)b * 16 * HW + s0 + px2;
#pragma unroll
    for (int r = 0; r < 4; r++)
        op[(lq * 4 + r) * HW] = fmaxf(acc2[r], 0.f);
}

// ---------------------------------------------------------------------------
// K5+K6 fused: 3x3 conv [16][16] + relu + 1x1 [1][16] + sigmoid, * cm -> ew
// grid (8,8,2), block 256.
__global__ __launch_bounds__(256, 4)
void k_cd1ew(const float* __restrict__ ga2, const float* __restrict__ w1t,
             const float* __restrict__ b1, const float* __restrict__ w2,
             const float* __restrict__ b2, const float* __restrict__ cm,
             float* __restrict__ ew) {
    __shared__ float lds[16][324];
    int tid = threadIdx.x;
    int tx = tid & 15, ty = tid >> 4;
    int x0 = blockIdx.x * 16, y0 = blockIdx.y * 16;
    int b = blockIdx.z;
    const float* ip = ga2 + (size_t)b * 16 * HW;
    float acc[16];
#pragma unroll
    for (int co = 0; co < 16; co++) acc[co] = b1[co];
#pragma unroll
    for (int ci = 0; ci < 16; ci++) {
        const float* sp = ip + ci * HW;
        for (int i = tid; i < 324; i += 256) {
            int yy = i / 18, xx = i - yy * 18;
            int gy = y0 - 1 + yy, gx = x0 - 1 + xx;
            lds[ci][i] = (gy >= 0 && gy < Hd && gx >= 0 && gx < Wd) ? sp[gy * Wd + gx] : 0.f;
        }
    }
    __syncthreads();
    for (int ci = 0; ci < 16; ci++) {
        const float* wp = w1t + ci * 9 * 16;
        float pv[9];
#pragma unroll
        for (int r = 0; r < 3; r++)
#pragma unroll
            for (int cx = 0; cx < 3; cx++)
                pv[r * 3 + cx] = lds[ci][(ty + r) * 18 + tx + cx];
#pragma unroll
        for (int t = 0; t < 9; t++)
#pragma unroll
            for (int co = 0; co < 16; co++)
                acc[co] = fmaf(pv[t], wp[t * 16 + co], acc[co]);
    }
    float e = b2[0];
#pragma unroll
    for (int co = 0; co < 16; co++) e = fmaf(fmaxf(acc[co], 0.f), w2[co], e);
    float sig = 1.f / (1.f + expf(-e));
    int sp = (y0 + ty) * Wd + x0 + tx;
    ew[b * HW + sp] = sig * cm[b * HW + sp];
}

// ---------------------------------------------------------------------------
// K7/K8: 3x3 conv [64][64] via bf16 MFMA implicit GEMM, tap-split.
// 8x8 output tile x 64 co, 4 waves (wave w -> co 16w..16w+15).
// LDS: 10x10x64 bf16 halo tile, ci-octet XOR-swizzled vs (rowlin&7).
// FINAL=0: relu -> bf16 NHWC out. FINAL=1: out = x + alpha*ew*acc (fp32 NCHW).
template <int FINAL>
__global__ __launch_bounds__(256, 2)
void k_conv64m(const unsigned short* __restrict__ inh,
               const unsigned short* __restrict__ wh,
               const float* __restrict__ bias,
               unsigned short* __restrict__ outh,
               float* __restrict__ outf,
               const float* __restrict__ x,
               const float* __restrict__ ew,
               const float* __restrict__ alpha_p) {
    __shared__ unsigned short tile[100 * 64];   // 12.8 KB
    int tid = threadIdx.x;
    int x0 = blockIdx.x * 8, y0 = blockIdx.y * 8;
    int b = blockIdx.z;
    const size_t ibase = (size_t)b * HW * 64;

    for (int i = tid; i < 800; i += 256) {
        int py = i / 80;
        int r = i - py * 80;
        int px = r >> 3, cg = r & 7;
        int gy = y0 - 1 + py, gx = x0 - 1 + px;
        uint4 v = {0u, 0u, 0u, 0u};
        if (gy >= 0 && gy < Hd && gx >= 0 && gx < Wd)
            v = *(const uint4*)(inh + ibase + (size_t)(gy * Wd + gx) * 64 + cg * 8);
        int rowlin = py * 10 + px;
        int scg = cg ^ (rowlin & 7);
        *(uint4*)(tile + rowlin * 64 + scg * 8) = v;
    }

    int lane = tid & 63;
    int wv = tid >> 6;
    int l15 = lane & 15, lq = lane >> 4;
    int co_base = wv * 16;

    s8v af[9][2];
#pragma unroll
    for (int t = 0; t < 9; t++)
#pragma unroll
        for (int h = 0; h < 2; h++)
            af[t][h] = *(const s8v*)(wh + ((t * 64 + co_base + l15) * 64 + h * 32 + lq * 8));

    f4v bv = *(const f4v*)(bias + co_base + lq * 4);
    f4v acc[4];
#pragma unroll
    for (int n = 0; n < 4; n++) acc[n] = bv;

    __syncthreads();

#pragma unroll
    for (int n = 0; n < 4; n++) {
        int px = n * 16 + l15;
        int pyy = px >> 3, pxx = px & 7;
#pragma unroll
        for (int dy = 0; dy < 3; dy++) {
#pragma unroll
            for (int dx = 0; dx < 3; dx++) {
                int rowlin = (pyy + dy) * 10 + (pxx + dx);
                int sw = rowlin & 7;
                const unsigned short* tp = tile + rowlin * 64;
                s8v b0 = *(const s8v*)(tp + (lq ^ sw) * 8);
                s8v b1 = *(const s8v*)(tp + ((4 + lq) ^ sw) * 8);
                int t = dy * 3 + dx;
                acc[n] = __builtin_amdgcn_mfma_f32_16x16x32_bf16(af[t][0], b0, acc[n], 0, 0, 0);
                acc[n] = __builtin_amdgcn_mfma_f32_16x16x32_bf16(af[t][1], b1, acc[n], 0, 0, 0);
            }
        }
    }

#pragma unroll
    for (int n = 0; n < 4; n++) {
        int px = n * 16 + l15;
        int gyo = y0 + (px >> 3), gxo = x0 + (px & 7);
        int sp = gyo * Wd + gxo;
        if (FINAL) {
            float ae = alpha_p[0] * ew[b * HW + sp];
#pragma unroll
            for (int r = 0; r < 4; r++) {
                size_t o = (size_t)(b * 64 + co_base + lq * 4 + r) * HW + sp;
                outf[o] = fmaf(ae, acc[n][r], x[o]);
            }
        } else {
            alignas(8) unsigned short pk[4];
#pragma unroll
            for (int r = 0; r < 4; r++) pk[r] = f2bf(fmaxf(acc[n][r], 0.f));
            *(uint2*)(outh + ibase + (size_t)sp * 64 + co_base + lq * 4) = *(const uint2*)pk;
        }
    }
}

// ---------------------------------------------------------------------------
extern "C" void kernel_launch(void* const* d_in, const int* in_sizes, int n_in,
                              void* d_out, int out_size, void* d_ws, size_t ws_size,
                              hipStream_t stream) {
    const float* x     = (const float*)d_in[0];
    const float* wgx   = (const float*)d_in[1];
    const float* wgy   = (const float*)d_in[2];
    const float* ga_w1 = (const float*)d_in[3];
    const float* ga_b1 = (const float*)d_in[4];
    const float* ga_w2 = (const float*)d_in[5];
    const float* ga_b2 = (const float*)d_in[6];
    const float* cd_w1 = (const float*)d_in[7];
    const float* cd_b1 = (const float*)d_in[8];
    const float* cd_w2 = (const float*)d_in[9];
    const float* cd_b2 = (const float*)d_in[10];
    const float* ec_w1 = (const float*)d_in[11];
    const float* ec_b1 = (const float*)d_in[12];
    const float* ec_w2 = (const float*)d_in[13];
    const float* ec_b2 = (const float*)d_in[14];
    const float* alpha = (const float*)d_in[15];
    float* out = (float*)d_out;
    float* ws  = (float*)d_ws;

    const size_t N = 2 * 64 * HW;   // 2,097,152 floats

    // buffer plan:
    unsigned short* gxgyh = (unsigned short*)ws;  // 2*HW px *128ch bf16 = N floats
    float* ga2   = ws + N;                        // 524288 floats
    float* cm    = ga2 + 2 * 16 * HW;             // 32768
    float* ew    = cm + 2 * HW;                   // 32768
    float* cd_w1t = ew + 2 * HW;                  // 2304
    unsigned short* w1h = (unsigned short*)(cd_w1t + 2304);  // 36864 shorts
    unsigned short* w2h = w1h + 36864;                       // 36864
    unsigned short* w1m = w2h + 36864;                       // 8192
    unsigned short* w2m = w1m + 8192;                        // 1024
    unsigned short* xh   = (unsigned short*)(ws + 2 * N);    // 2M shorts
    unsigned short* ee1h = xh + N;                           // 2M shorts

    k_prepxh<<<590, 256, 0, stream>>>(x, ga_w1, ga_w2, cd_w1, ec_w1, ec_w2,
                                      xh, w1m, w2m, cd_w1t, w1h, w2h, cm);
    k_sobcons<<<dim3(8, 8, 32), 256, 0, stream>>>(x, wgx, wgy, gxgyh, cm);
    k_gam<<<512, 256, 0, stream>>>(gxgyh, w1m, ga_b1, w2m, ga_b2, ga2);
    k_cd1ew<<<dim3(8, 8, 2), 256, 0, stream>>>(ga2, cd_w1t, cd_b1, cd_w2, cd_b2, cm, ew);
    k_conv64m<0><<<dim3(16, 16, 2), 256, 0, stream>>>(xh, w1h, ec_b1, ee1h,
                                                      nullptr, nullptr, nullptr, nullptr);
    k_conv64m<1><<<dim3(16, 16, 2), 256, 0, stream>>>(ee1h, w2h, ec_b2, nullptr,
                                                      out, x, ew, alpha);
}

// Round 11
// 158.034 us; speedup vs baseline: 1.4534x; 1.0573x over previous
//
#include <hip/hip_runtime.h>
#include <math.h>

#define Hd 128
#define Wd 128
#define HW 16384      // 128*128
#define EPSc 1e-6f

typedef __attribute__((ext_vector_type(8))) short s8v;    // 8 bf16 (4 VGPRs)
typedef __attribute__((ext_vector_type(4))) float f4v;    // 4 fp32

__device__ __forceinline__ unsigned short f2bf(float f) {
    unsigned int u = __float_as_uint(f);
    unsigned int r = (u + 0x7FFFu + ((u >> 16) & 1u)) >> 16;   // RNE
    return (unsigned short)r;
}

__device__ __forceinline__ float rcpf(float x) { return __builtin_amdgcn_rcpf(x); }

// fast atan2, max err ~1e-5 rad (A&S 4.4.49 deg-9 on [0,1] + quadrant fixup)
__device__ __forceinline__ float fatan2(float sy, float sx) {
    float ax = fabsf(sx), ay = fabsf(sy);
    float mx = fmaxf(ax, ay), mn = fminf(ax, ay);
    float q = mn * rcpf(mx);
    float s = q * q;
    float r = q * fmaf(s, fmaf(s, fmaf(s, fmaf(s, 0.0208351f, -0.0851330f),
                                       0.1801410f), -0.3302995f), 0.9998660f);
    if (ay > ax) r = 1.5707963268f - r;
    if (sx < 0.f) r = 3.14159265359f - r;
    r = (sy < 0.f) ? -r : r;
    return (mx == 0.f) ? 0.f : r;
}

// ---------------------------------------------------------------------------
// K_A: 3 roles by blockIdx.x.
//  [0,2048):    sobcons — sobel + 5x5 weighted circular-variance; writes
//               gx/gy as bf16 NHWC[p][128] and NON-ATOMIC per-quadrant
//               channel-mean partials cmPart[b*16+q][px] (no cm-zero needed).
//  [2048,2560): x NCHW fp32 -> xh NHWC bf16 (16 ch/thread).
//  [2560,2893): weight prep (bf16 casts / transposes).
__global__ __launch_bounds__(256, 8)
void k_A(const float* __restrict__ x,
         const float* __restrict__ wgx, const float* __restrict__ wgy,
         const float* __restrict__ ga_w1, const float* __restrict__ ga_w2,
         const float* __restrict__ cd_w1,
         const float* __restrict__ ec_w1, const float* __restrict__ ec_w2,
         unsigned short* __restrict__ gxgyh, float* __restrict__ cmPart,
         unsigned short* __restrict__ xh,
         unsigned short* __restrict__ w1m, unsigned short* __restrict__ w2m,
         float* __restrict__ cd_w1t,
         unsigned short* __restrict__ w1h, unsigned short* __restrict__ w2h) {
    __shared__ float xt[484];        // 22x22 x-tile (3-halo)
    __shared__ float lm[480];        // 20 rows x stride 24
    __shared__ float ld[480];
    int bid = blockIdx.x;
    int tid = threadIdx.x;

    if (bid < 2048) {                // ---------------- sobcons role
        int bx = bid & 7, by = (bid >> 3) & 7, z = bid >> 6;
        int tx = tid & 15, ty = tid >> 4;
        int x0 = bx * 16, y0 = by * 16;
        int b = z >> 4, cb = (z & 15) * 4;
        float acc = 0.f;
        for (int c = 0; c < 4; c++) {
            int ch = cb + c;
            const float* xp = x + (size_t)(b * 64 + ch) * HW;
            float wx[9], wy[9];
#pragma unroll
            for (int i = 0; i < 9; i++) { wx[i] = wgx[ch * 9 + i]; wy[i] = wgy[ch * 9 + i]; }
            __syncthreads();    // previous channel's cons reads done
            for (int i = tid; i < 484; i += 256) {
                int yy = i / 22, xx = i - yy * 22;
                int gyy = y0 - 3 + yy, gxx = x0 - 3 + xx;
                xt[i] = (gyy >= 0 && gyy < Hd && gxx >= 0 && gxx < Wd) ? xp[gyy * Wd + gxx] : 0.f;
            }
            __syncthreads();
            for (int i = tid; i < 400; i += 256) {
                int yy = i / 20, xx = i - yy * 20;
                int gyy = y0 - 2 + yy, gxx = x0 - 2 + xx;
                float m = 0.f, d = 0.f, sx = 0.f, sy = 0.f;
                if (gyy >= 0 && gyy < Hd && gxx >= 0 && gxx < Wd) {
#pragma unroll
                    for (int dy = 0; dy < 3; dy++)
#pragma unroll
                        for (int dx = 0; dx < 3; dx++) {
                            float v = xt[(yy + dy) * 22 + xx + dx];
                            sx = fmaf(wx[dy * 3 + dx], v, sx);
                            sy = fmaf(wy[dy * 3 + dx], v, sy);
                        }
                    m = sqrtf(sx * sx + sy * sy + EPSc);
                    d = fatan2(sy, sx);
                }
                lm[yy * 24 + xx] = m;
                ld[yy * 24 + xx] = d;
                if (yy >= 2 && yy < 18 && xx >= 2 && xx < 18) {
                    size_t pb = ((size_t)b * HW + gyy * Wd + gxx) * 128;
                    gxgyh[pb + ch] = f2bf(sx);
                    gxgyh[pb + 64 + ch] = f2bf(sy);
                }
            }
            __syncthreads();
            float mv[25], dv[25];
            float sm = 0.f, sdm = 0.f;
#pragma unroll
            for (int r = 0; r < 5; r++)
#pragma unroll
                for (int cx = 0; cx < 5; cx++) {
                    int idx = (ty + r) * 24 + tx + cx;
                    float m = lm[idx], d = ld[idx];
                    mv[r * 5 + cx] = m;
                    dv[r * 5 + cx] = d;
                    sm += m;
                    sdm = fmaf(d, m, sdm);
                }
            float rinv = rcpf(sm + EPSc);
            float wmean = sdm * rinv;
            float sv = 0.f;
#pragma unroll
            for (int t = 0; t < 25; t++) { float dd = dv[t] - wmean; sv = fmaf(dd * dd, mv[t], sv); }
            float wstd = sqrtf(sv * rinv);
            acc += 2.f * rcpf(__expf(2.f * wstd) + 1.f);   // = 1 - tanh(wstd)
        }
        cmPart[(size_t)z * HW + (y0 + ty) * Wd + x0 + tx] = acc * (1.f / 64.f);
        return;
    }
    if (bid < 2560) {                // ---------------- xh role (16 ch/thread)
        int idx = (bid - 2048) * 256 + tid;    // [0, 131072)
        int cg = idx >> 15;                    // 16-ch group 0..3
        int p  = idx & 32767;
        int b = p >> 14, s = p & (HW - 1);
        const float* xp = x + ((size_t)b * 64 + cg * 16) * HW + s;
        alignas(16) unsigned short buf[16];
#pragma unroll
        for (int k = 0; k < 16; k++) buf[k] = f2bf(xp[k * HW]);
        uint4* dst = (uint4*)(xh + (size_t)p * 64 + cg * 16);
        dst[0] = ((const uint4*)buf)[0];
        dst[1] = ((const uint4*)buf)[1];
        return;
    }
    int i = (bid - 2560) * 256 + tid;          // ------- weight prep
    if (i < 36864) {                               // w1h [t][co][ci] bf16 (ec_w1)
        int t = i >> 12, co = (i >> 6) & 63, ci = i & 63;
        w1h[i] = f2bf(ec_w1[(co * 64 + ci) * 9 + t]);
    } else if (i < 73728) {                        // w2h (ec_w2)
        int j = i - 36864;
        int t = j >> 12, co = (j >> 6) & 63, ci = j & 63;
        w2h[j] = f2bf(ec_w2[(co * 64 + ci) * 9 + t]);
    } else if (i < 81920) {                        // w1m [co64][K128] = ga_w1 cast
        int j = i - 73728;
        w1m[j] = f2bf(ga_w1[j]);
    } else if (i < 82944) {                        // w2m [co16][ci64] = ga_w2 cast
        int j = i - 81920;
        w2m[j] = f2bf(ga_w2[j]);
    } else if (i < 85248) {                        // cd_w1t [ci16][tap9][co16] fp32
        int j = i - 82944;
        int co = j & 15, r = j >> 4, t = r % 9, ci = r / 9;
        cd_w1t[j] = cd_w1[(co * 16 + ci) * 9 + t];
    }
}

// ---------------------------------------------------------------------------
// K_B: 2 roles by blockIdx.x (LDS union 24 KB).
//  [0,512):    conv64m FINAL=0 (3x3 64->64 MFMA, relu -> bf16 NHWC ee1h)
//  [512,1024): gam — ga1+ga2 fused MFMA GEMM -> ga2 fp32 NCHW
__global__ __launch_bounds__(256, 2)
void k_B(const unsigned short* __restrict__ xh,
         const unsigned short* __restrict__ w1h, const float* __restrict__ ec_b1,
         unsigned short* __restrict__ ee1h,
         const unsigned short* __restrict__ gxgyh,
         const unsigned short* __restrict__ w1m, const float* __restrict__ b1,
         const unsigned short* __restrict__ w2m, const float* __restrict__ b2,
         float* __restrict__ ga2) {
    __shared__ unsigned short shb[12288];   // 24 KB union
    int bid = blockIdx.x;
    int tid = threadIdx.x;
    int lane = tid & 63, wv = tid >> 6;
    int l15 = lane & 15, lq = lane >> 4;

    if (bid < 512) {                 // ---------------- conv64m<0> role
        unsigned short* tile = shb;  // 100x64 bf16, 12.8 KB
        int j = bid;
        int x0 = (j & 15) * 8, y0 = ((j >> 4) & 15) * 8;
        int b = j >> 8;
        const size_t ibase = (size_t)b * HW * 64;

        for (int i = tid; i < 800; i += 256) {
            int py = i / 80;
            int r = i - py * 80;
            int px = r >> 3, cg = r & 7;
            int gy = y0 - 1 + py, gx = x0 - 1 + px;
            uint4 v = {0u, 0u, 0u, 0u};
            if (gy >= 0 && gy < Hd && gx >= 0 && gx < Wd)
                v = *(const uint4*)(xh + ibase + (size_t)(gy * Wd + gx) * 64 + cg * 8);
            int rowlin = py * 10 + px;
            int scg = cg ^ (rowlin & 7);
            *(uint4*)(tile + rowlin * 64 + scg * 8) = v;
        }
        int co_base = wv * 16;
        s8v af[9][2];
#pragma unroll
        for (int t = 0; t < 9; t++)
#pragma unroll
            for (int h = 0; h < 2; h++)
                af[t][h] = *(const s8v*)(w1h + ((t * 64 + co_base + l15) * 64 + h * 32 + lq * 8));
        f4v bv = *(const f4v*)(ec_b1 + co_base + lq * 4);
        f4v acc[4];
#pragma unroll
        for (int n = 0; n < 4; n++) acc[n] = bv;
        __syncthreads();
#pragma unroll
        for (int n = 0; n < 4; n++) {
            int px = n * 16 + l15;
            int pyy = px >> 3, pxx = px & 7;
#pragma unroll
            for (int dy = 0; dy < 3; dy++) {
#pragma unroll
                for (int dx = 0; dx < 3; dx++) {
                    int rowlin = (pyy + dy) * 10 + (pxx + dx);
                    int sw = rowlin & 7;
                    const unsigned short* tp = tile + rowlin * 64;
                    s8v b0 = *(const s8v*)(tp + (lq ^ sw) * 8);
                    s8v b1v = *(const s8v*)(tp + ((4 + lq) ^ sw) * 8);
                    int t = dy * 3 + dx;
                    acc[n] = __builtin_amdgcn_mfma_f32_16x16x32_bf16(af[t][0], b0, acc[n], 0, 0, 0);
                    acc[n] = __builtin_amdgcn_mfma_f32_16x16x32_bf16(af[t][1], b1v, acc[n], 0, 0, 0);
                }
            }
        }
#pragma unroll
        for (int n = 0; n < 4; n++) {
            int px = n * 16 + l15;
            int sp = (y0 + (px >> 3)) * Wd + x0 + (px & 7);
            alignas(8) unsigned short pk[4];
#pragma unroll
            for (int r = 0; r < 4; r++) pk[r] = f2bf(fmaxf(acc[n][r], 0.f));
            *(uint2*)(ee1h + ibase + (size_t)sp * 64 + co_base + lq * 4) = *(const uint2*)pk;
        }
        return;
    }

    // -------------------------------- gam role
    unsigned short* la = shb;            // 64x128 bf16, 16 KB
    unsigned short* lp = shb + 8192;     // 64x64 bf16, 8 KB
    int p0 = (bid - 512) * 64;
    int b = p0 >> 14;
    int s0 = p0 & (HW - 1);

    const unsigned short* src = gxgyh + (size_t)p0 * 128;
    for (int i = tid; i < 1024; i += 256) {
        int px = i >> 4, cg = i & 15;
        uint4 v = *(const uint4*)(src + px * 128 + cg * 8);
        *(uint4*)(la + px * 128 + ((cg ^ (px & 15)) * 8)) = v;
    }
    int co_base = wv * 16;
    s8v af[4];
#pragma unroll
    for (int h = 0; h < 4; h++)
        af[h] = *(const s8v*)(w1m + (co_base + l15) * 128 + h * 32 + lq * 8);
    f4v bv = *(const f4v*)(b1 + co_base + lq * 4);
    f4v acc[4];
#pragma unroll
    for (int n = 0; n < 4; n++) acc[n] = bv;
    __syncthreads();
#pragma unroll
    for (int n = 0; n < 4; n++) {
        const unsigned short* tp = la + (n * 16 + l15) * 128;
#pragma unroll
        for (int h = 0; h < 4; h++) {
            s8v bb = *(const s8v*)(tp + (((h * 4 + lq) ^ l15) * 8));
            acc[n] = __builtin_amdgcn_mfma_f32_16x16x32_bf16(af[h], bb, acc[n], 0, 0, 0);
        }
    }
    int co = co_base + lq * 4;
    int og = co >> 3;
#pragma unroll
    for (int n = 0; n < 4; n++) {
        int px = n * 16 + l15;
        alignas(8) unsigned short pk[4];
#pragma unroll
        for (int r = 0; r < 4; r++) pk[r] = f2bf(fmaxf(acc[n][r], 0.f));
        *(uint2*)(lp + px * 64 + ((og ^ (px & 7)) * 8) + (co & 7)) = *(const uint2*)pk;
    }
    __syncthreads();
    s8v af2[2];
#pragma unroll
    for (int h = 0; h < 2; h++)
        af2[h] = *(const s8v*)(w2m + l15 * 64 + h * 32 + lq * 8);
    f4v acc2 = *(const f4v*)(b2 + lq * 4);
    int px2 = wv * 16 + l15;
    const unsigned short* tp2 = lp + px2 * 64;
#pragma unroll
    for (int h = 0; h < 2; h++) {
        s8v bb = *(const s8v*)(tp2 + (((h * 4 + lq) ^ (px2 & 7)) * 8));
        acc2 = __builtin_amdgcn_mfma_f32_16x16x32_bf16(af2[h], bb, acc2, 0, 0, 0);
    }
    float* op = ga2 + (size_t)b * 16 * HW + s0 + px2;
#pragma unroll
    for (int r = 0; r < 4; r++)
        op[(lq * 4 + r) * HW] = fmaxf(acc2[r], 0.f);
}

// ---------------------------------------------------------------------------
// K_C: 3x3 conv [16][16] + relu + 1x1 [1][16] + sigmoid, * sum(cmPart) -> ew
// grid (8,8,2), block 256.
__global__ __launch_bounds__(256, 4)
void k_cd1ew(const float* __restrict__ ga2, const float* __restrict__ w1t,
             const float* __restrict__ b1, const float* __restrict__ w2,
             const float* __restrict__ b2, const float* __restrict__ cmPart,
             float* __restrict__ ew) {
    __shared__ float lds[16][324];
    int tid = threadIdx.x;
    int tx = tid & 15, ty = tid >> 4;
    int x0 = blockIdx.x * 16, y0 = blockIdx.y * 16;
    int b = blockIdx.z;
    const float* ip = ga2 + (size_t)b * 16 * HW;
    float acc[16];
#pragma unroll
    for (int co = 0; co < 16; co++) acc[co] = b1[co];
#pragma unroll
    for (int ci = 0; ci < 16; ci++) {
        const float* sp = ip + ci * HW;
        for (int i = tid; i < 324; i += 256) {
            int yy = i / 18, xx = i - yy * 18;
            int gy = y0 - 1 + yy, gx = x0 - 1 + xx;
            lds[ci][i] = (gy >= 0 && gy < Hd && gx >= 0 && gx < Wd) ? sp[gy * Wd + gx] : 0.f;
        }
    }
    __syncthreads();
    for (int ci = 0; ci < 16; ci++) {
        const float* wp = w1t + ci * 9 * 16;
        float pv[9];
#pragma unroll
        for (int r = 0; r < 3; r++)
#pragma unroll
            for (int cx = 0; cx < 3; cx++)
                pv[r * 3 + cx] = lds[ci][(ty + r) * 18 + tx + cx];
#pragma unroll
        for (int t = 0; t < 9; t++)
#pragma unroll
            for (int co = 0; co < 16; co++)
                acc[co] = fmaf(pv[t], wp[t * 16 + co], acc[co]);
    }
    float e = b2[0];
#pragma unroll
    for (int co = 0; co < 16; co++) e = fmaf(fmaxf(acc[co], 0.f), w2[co], e);
    float sig = rcpf(1.f + __expf(-e));
    int sp = (y0 + ty) * Wd + x0 + tx;
    float cmv = 0.f;
#pragma unroll
    for (int q = 0; q < 16; q++) cmv += cmPart[(size_t)((b << 4) + q) * HW + sp];
    ew[b * HW + sp] = sig * cmv;
}

// ---------------------------------------------------------------------------
// K_D: 3x3 conv [64][64] MFMA, epilogue out = x + alpha*ew*acc (fp32 NCHW).
__global__ __launch_bounds__(256, 2)
void k_conv64f(const unsigned short* __restrict__ inh,
               const unsigned short* __restrict__ wh,
               const float* __restrict__ bias,
               float* __restrict__ outf,
               const float* __restrict__ x,
               const float* __restrict__ ew,
               const float* __restrict__ alpha_p) {
    __shared__ unsigned short tile[100 * 64];   // 12.8 KB
    int tid = threadIdx.x;
    int x0 = blockIdx.x * 8, y0 = blockIdx.y * 8;
    int b = blockIdx.z;
    const size_t ibase = (size_t)b * HW * 64;

    for (int i = tid; i < 800; i += 256) {
        int py = i / 80;
        int r = i - py * 80;
        int px = r >> 3, cg = r & 7;
        int gy = y0 - 1 + py, gx = x0 - 1 + px;
        uint4 v = {0u, 0u, 0u, 0u};
        if (gy >= 0 && gy < Hd && gx >= 0 && gx < Wd)
            v = *(const uint4*)(inh + ibase + (size_t)(gy * Wd + gx) * 64 + cg * 8);
        int rowlin = py * 10 + px;
        int scg = cg ^ (rowlin & 7);
        *(uint4*)(tile + rowlin * 64 + scg * 8) = v;
    }
    int lane = tid & 63;
    int wv = tid >> 6;
    int l15 = lane & 15, lq = lane >> 4;
    int co_base = wv * 16;
    s8v af[9][2];
#pragma unroll
    for (int t = 0; t < 9; t++)
#pragma unroll
        for (int h = 0; h < 2; h++)
            af[t][h] = *(const s8v*)(wh + ((t * 64 + co_base + l15) * 64 + h * 32 + lq * 8));
    f4v bv = *(const f4v*)(bias + co_base + lq * 4);
    f4v acc[4];
#pragma unroll
    for (int n = 0; n < 4; n++) acc[n] = bv;
    __syncthreads();
#pragma unroll
    for (int n = 0; n < 4; n++) {
        int px = n * 16 + l15;
        int pyy = px >> 3, pxx = px & 7;
#pragma unroll
        for (int dy = 0; dy < 3; dy++) {
#pragma unroll
            for (int dx = 0; dx < 3; dx++) {
                int rowlin = (pyy + dy) * 10 + (pxx + dx);
                int sw = rowlin & 7;
                const unsigned short* tp = tile + rowlin * 64;
                s8v b0 = *(const s8v*)(tp + (lq ^ sw) * 8);
                s8v b1v = *(const s8v*)(tp + ((4 + lq) ^ sw) * 8);
                int t = dy * 3 + dx;
                acc[n] = __builtin_amdgcn_mfma_f32_16x16x32_bf16(af[t][0], b0, acc[n], 0, 0, 0);
                acc[n] = __builtin_amdgcn_mfma_f32_16x16x32_bf16(af[t][1], b1v, acc[n], 0, 0, 0);
            }
        }
    }
#pragma unroll
    for (int n = 0; n < 4; n++) {
        int px = n * 16 + l15;
        int sp = (y0 + (px >> 3)) * Wd + x0 + (px & 7);
        float ae = alpha_p[0] * ew[b * HW + sp];
#pragma unroll
        for (int r = 0; r < 4; r++) {
            size_t o = (size_t)(b * 64 + co_base + lq * 4 + r) * HW + sp;
            outf[o] = fmaf(ae, acc[n][r], x[o]);
        }
    }
}

// ---------------------------------------------------------------------------
extern "C" void kernel_launch(void* const* d_in, const int* in_sizes, int n_in,
                              void* d_out, int out_size, void* d_ws, size_t ws_size,
                              hipStream_t stream) {
    const float* x     = (const float*)d_in[0];
    const float* wgx   = (const float*)d_in[1];
    const float* wgy   = (const float*)d_in[2];
    const float* ga_w1 = (const float*)d_in[3];
    const float* ga_b1 = (const float*)d_in[4];
    const float* ga_w2 = (const float*)d_in[5];
    const float* ga_b2 = (const float*)d_in[6];
    const float* cd_w1 = (const float*)d_in[7];
    const float* cd_b1 = (const float*)d_in[8];
    const float* cd_w2 = (const float*)d_in[9];
    const float* cd_b2 = (const float*)d_in[10];
    const float* ec_w1 = (const float*)d_in[11];
    const float* ec_b1 = (const float*)d_in[12];
    const float* ec_w2 = (const float*)d_in[13];
    const float* ec_b2 = (const float*)d_in[14];
    const float* alpha = (const float*)d_in[15];
    float* out = (float*)d_out;
    float* ws  = (float*)d_ws;

    const size_t N = 2 * 64 * HW;   // 2,097,152 floats

    // buffer plan:
    unsigned short* gxgyh = (unsigned short*)ws;  // 2*HW px * 128ch bf16 = N floats
    float* ga2    = ws + N;                       // 524288 floats
    float* cmPart = ga2 + 2 * 16 * HW;            // 32 slices x HW = 524288 floats
    float* ew     = cmPart + 32 * HW;             // 32768
    float* cd_w1t = ew + 2 * HW;                  // 2304
    unsigned short* w1h = (unsigned short*)(cd_w1t + 2304);  // 36864 shorts
    unsigned short* w2h = w1h + 36864;                       // 36864
    unsigned short* w1m = w2h + 36864;                       // 8192
    unsigned short* w2m = w1m + 8192;                        // 1024
    unsigned short* xh   = (unsigned short*)(ws + 2 * N);    // 2M shorts
    unsigned short* ee1h = xh + N;                           // 2M shorts

    k_A<<<2893, 256, 0, stream>>>(x, wgx, wgy, ga_w1, ga_w2, cd_w1, ec_w1, ec_w2,
                                  gxgyh, cmPart, xh, w1m, w2m, cd_w1t, w1h, w2h);
    k_B<<<1024, 256, 0, stream>>>(xh, w1h, ec_b1, ee1h,
                                  gxgyh, w1m, ga_b1, w2m, ga_b2, ga2);
    k_cd1ew<<<dim3(8, 8, 2), 256, 0, stream>>>(ga2, cd_w1t, cd_b1, cd_w2, cd_b2,
                                               cmPart, ew);
    k_conv64f<<<dim3(16, 16, 2), 256, 0, stream>>>(ee1h, w2h, ec_b2, out, x, ew, alpha);
}

// Round 12
// 150.742 us; speedup vs baseline: 1.5238x; 1.0484x over previous
//
#include <hip/hip_runtime.h>
#include <math.h>

#define Hd 128
#define Wd 128
#define HW 16384      // 128*128
#define EPSc 1e-6f

typedef __attribute__((ext_vector_type(8))) short s8v;    // 8 bf16 (4 VGPRs)
typedef __attribute__((ext_vector_type(4))) float f4v;    // 4 fp32

__device__ __forceinline__ unsigned short f2bf(float f) {
    unsigned int u = __float_as_uint(f);
    unsigned int r = (u + 0x7FFFu + ((u >> 16) & 1u)) >> 16;   // RNE
    return (unsigned short)r;
}

__device__ __forceinline__ float rcpf(float x) { return __builtin_amdgcn_rcpf(x); }

// fast atan2, max err ~1e-5 rad (A&S 4.4.49 deg-9 on [0,1] + quadrant fixup)
__device__ __forceinline__ float fatan2(float sy, float sx) {
    float ax = fabsf(sx), ay = fabsf(sy);
    float mx = fmaxf(ax, ay), mn = fminf(ax, ay);
    float q = mn * rcpf(mx);
    float s = q * q;
    float r = q * fmaf(s, fmaf(s, fmaf(s, fmaf(s, 0.0208351f, -0.0851330f),
                                       0.1801410f), -0.3302995f), 0.9998660f);
    if (ay > ax) r = 1.5707963268f - r;
    if (sx < 0.f) r = 3.14159265359f - r;
    r = (sy < 0.f) ? -r : r;
    return (mx == 0.f) ? 0.f : r;
}

// ---------------------------------------------------------------------------
// K_A: 3 roles by blockIdx.x.
//  [0,2048):    sobcons — sobel + 5x5 weighted circular-variance; writes
//               gx/gy as bf16 NHWC[p][128] and NON-ATOMIC per-quadrant
//               channel-mean partials cmPart[b*16+q][px].
//  [2048,2560): x NCHW fp32 -> xh NHWC bf16 (16 ch/thread).
//  [2560,2893): weight prep (bf16 casts / transposes).
__global__ __launch_bounds__(256, 8)
void k_A(const float* __restrict__ x,
         const float* __restrict__ wgx, const float* __restrict__ wgy,
         const float* __restrict__ ga_w1, const float* __restrict__ ga_w2,
         const float* __restrict__ cd_w1,
         const float* __restrict__ ec_w1, const float* __restrict__ ec_w2,
         unsigned short* __restrict__ gxgyh, float* __restrict__ cmPart,
         unsigned short* __restrict__ xh,
         unsigned short* __restrict__ w1m, unsigned short* __restrict__ w2m,
         float* __restrict__ cd_w1t,
         unsigned short* __restrict__ w1h, unsigned short* __restrict__ w2h) {
    __shared__ float xt[484];        // 22x22 x-tile (3-halo)
    __shared__ float lm[480];        // 20 rows x stride 24
    __shared__ float ld[480];
    int bid = blockIdx.x;
    int tid = threadIdx.x;

    if (bid < 2048) {                // ---------------- sobcons role
        int bx = bid & 7, by = (bid >> 3) & 7, z = bid >> 6;
        int tx = tid & 15, ty = tid >> 4;
        int x0 = bx * 16, y0 = by * 16;
        int b = z >> 4, cb = (z & 15) * 4;
        float acc = 0.f;
        for (int c = 0; c < 4; c++) {
            int ch = cb + c;
            const float* xp = x + (size_t)(b * 64 + ch) * HW;
            float wx[9], wy[9];
#pragma unroll
            for (int i = 0; i < 9; i++) { wx[i] = wgx[ch * 9 + i]; wy[i] = wgy[ch * 9 + i]; }
            __syncthreads();    // previous channel's cons reads done
            for (int i = tid; i < 484; i += 256) {
                int yy = i / 22, xx = i - yy * 22;
                int gyy = y0 - 3 + yy, gxx = x0 - 3 + xx;
                xt[i] = (gyy >= 0 && gyy < Hd && gxx >= 0 && gxx < Wd) ? xp[gyy * Wd + gxx] : 0.f;
            }
            __syncthreads();
            for (int i = tid; i < 400; i += 256) {
                int yy = i / 20, xx = i - yy * 20;
                int gyy = y0 - 2 + yy, gxx = x0 - 2 + xx;
                float m = 0.f, d = 0.f, sx = 0.f, sy = 0.f;
                if (gyy >= 0 && gyy < Hd && gxx >= 0 && gxx < Wd) {
#pragma unroll
                    for (int dy = 0; dy < 3; dy++)
#pragma unroll
                        for (int dx = 0; dx < 3; dx++) {
                            float v = xt[(yy + dy) * 22 + xx + dx];
                            sx = fmaf(wx[dy * 3 + dx], v, sx);
                            sy = fmaf(wy[dy * 3 + dx], v, sy);
                        }
                    m = sqrtf(sx * sx + sy * sy + EPSc);
                    d = fatan2(sy, sx);
                }
                lm[yy * 24 + xx] = m;
                ld[yy * 24 + xx] = d;
                if (yy >= 2 && yy < 18 && xx >= 2 && xx < 18) {
                    size_t pb = ((size_t)b * HW + gyy * Wd + gxx) * 128;
                    gxgyh[pb + ch] = f2bf(sx);
                    gxgyh[pb + 64 + ch] = f2bf(sy);
                }
            }
            __syncthreads();
            float mv[25], dv[25];
            float sm = 0.f, sdm = 0.f;
#pragma unroll
            for (int r = 0; r < 5; r++)
#pragma unroll
                for (int cx = 0; cx < 5; cx++) {
                    int idx = (ty + r) * 24 + tx + cx;
                    float m = lm[idx], d = ld[idx];
                    mv[r * 5 + cx] = m;
                    dv[r * 5 + cx] = d;
                    sm += m;
                    sdm = fmaf(d, m, sdm);
                }
            float rinv = rcpf(sm + EPSc);
            float wmean = sdm * rinv;
            float sv = 0.f;
#pragma unroll
            for (int t = 0; t < 25; t++) { float dd = dv[t] - wmean; sv = fmaf(dd * dd, mv[t], sv); }
            float wstd = sqrtf(sv * rinv);
            acc += 2.f * rcpf(__expf(2.f * wstd) + 1.f);   // = 1 - tanh(wstd)
        }
        cmPart[(size_t)z * HW + (y0 + ty) * Wd + x0 + tx] = acc * (1.f / 64.f);
        return;
    }
    if (bid < 2560) {                // ---------------- xh role (16 ch/thread)
        int idx = (bid - 2048) * 256 + tid;    // [0, 131072)
        int cg = idx >> 15;                    // 16-ch group 0..3
        int p  = idx & 32767;
        int b = p >> 14, s = p & (HW - 1);
        const float* xp = x + ((size_t)b * 64 + cg * 16) * HW + s;
        alignas(16) unsigned short buf[16];
#pragma unroll
        for (int k = 0; k < 16; k++) buf[k] = f2bf(xp[k * HW]);
        uint4* dst = (uint4*)(xh + (size_t)p * 64 + cg * 16);
        dst[0] = ((const uint4*)buf)[0];
        dst[1] = ((const uint4*)buf)[1];
        return;
    }
    int i = (bid - 2560) * 256 + tid;          // ------- weight prep
    if (i < 36864) {                               // w1h [t][co][ci] bf16 (ec_w1)
        int t = i >> 12, co = (i >> 6) & 63, ci = i & 63;
        w1h[i] = f2bf(ec_w1[(co * 64 + ci) * 9 + t]);
    } else if (i < 73728) {                        // w2h (ec_w2)
        int j = i - 36864;
        int t = j >> 12, co = (j >> 6) & 63, ci = j & 63;
        w2h[j] = f2bf(ec_w2[(co * 64 + ci) * 9 + t]);
    } else if (i < 81920) {                        // w1m [co64][K128] = ga_w1 cast
        int j = i - 73728;
        w1m[j] = f2bf(ga_w1[j]);
    } else if (i < 82944) {                        // w2m [co16][ci64] = ga_w2 cast
        int j = i - 81920;
        w2m[j] = f2bf(ga_w2[j]);
    } else if (i < 85248) {                        // cd_w1t [ci16][tap9][co16] fp32
        int j = i - 82944;
        int co = j & 15, r = j >> 4, t = r % 9, ci = r / 9;
        cd_w1t[j] = cd_w1[(co * 16 + ci) * 9 + t];
    }
}

// ---------------------------------------------------------------------------
// K_B: 2 roles by blockIdx.x (LDS union 24 KB).
//  [0,512):    conv64 stage-1 (3x3 64->64 MFMA, relu -> bf16 NHWC ee1h)
//  [512,1024): gam — ga1+ga2 fused MFMA GEMM -> ga2 fp32 NCHW
__global__ __launch_bounds__(256, 2)
void k_B(const unsigned short* __restrict__ xh,
         const unsigned short* __restrict__ w1h, const float* __restrict__ ec_b1,
         unsigned short* __restrict__ ee1h,
         const unsigned short* __restrict__ gxgyh,
         const unsigned short* __restrict__ w1m, const float* __restrict__ b1,
         const unsigned short* __restrict__ w2m, const float* __restrict__ b2,
         float* __restrict__ ga2) {
    __shared__ unsigned short shb[12288];   // 24 KB union
    int bid = blockIdx.x;
    int tid = threadIdx.x;
    int lane = tid & 63, wv = tid >> 6;
    int l15 = lane & 15, lq = lane >> 4;

    if (bid < 512) {                 // ---------------- conv64 stage-1 role
        unsigned short* tile = shb;  // 100x64 bf16, 12.8 KB
        int j = bid;
        int x0 = (j & 15) * 8, y0 = ((j >> 4) & 15) * 8;
        int b = j >> 8;
        const size_t ibase = (size_t)b * HW * 64;

        for (int i = tid; i < 800; i += 256) {
            int py = i / 80;
            int r = i - py * 80;
            int px = r >> 3, cg = r & 7;
            int gy = y0 - 1 + py, gx = x0 - 1 + px;
            uint4 v = {0u, 0u, 0u, 0u};
            if (gy >= 0 && gy < Hd && gx >= 0 && gx < Wd)
                v = *(const uint4*)(xh + ibase + (size_t)(gy * Wd + gx) * 64 + cg * 8);
            int rowlin = py * 10 + px;
            int scg = cg ^ (rowlin & 7);
            *(uint4*)(tile + rowlin * 64 + scg * 8) = v;
        }
        int co_base = wv * 16;
        s8v af[9][2];
#pragma unroll
        for (int t = 0; t < 9; t++)
#pragma unroll
            for (int h = 0; h < 2; h++)
                af[t][h] = *(const s8v*)(w1h + ((t * 64 + co_base + l15) * 64 + h * 32 + lq * 8));
        f4v bv = *(const f4v*)(ec_b1 + co_base + lq * 4);
        f4v acc[4];
#pragma unroll
        for (int n = 0; n < 4; n++) acc[n] = bv;
        __syncthreads();
#pragma unroll
        for (int n = 0; n < 4; n++) {
            int px = n * 16 + l15;
            int pyy = px >> 3, pxx = px & 7;
#pragma unroll
            for (int dy = 0; dy < 3; dy++) {
#pragma unroll
                for (int dx = 0; dx < 3; dx++) {
                    int rowlin = (pyy + dy) * 10 + (pxx + dx);
                    int sw = rowlin & 7;
                    const unsigned short* tp = tile + rowlin * 64;
                    s8v b0 = *(const s8v*)(tp + (lq ^ sw) * 8);
                    s8v b1v = *(const s8v*)(tp + ((4 + lq) ^ sw) * 8);
                    int t = dy * 3 + dx;
                    acc[n] = __builtin_amdgcn_mfma_f32_16x16x32_bf16(af[t][0], b0, acc[n], 0, 0, 0);
                    acc[n] = __builtin_amdgcn_mfma_f32_16x16x32_bf16(af[t][1], b1v, acc[n], 0, 0, 0);
                }
            }
        }
#pragma unroll
        for (int n = 0; n < 4; n++) {
            int px = n * 16 + l15;
            int sp = (y0 + (px >> 3)) * Wd + x0 + (px & 7);
            alignas(8) unsigned short pk[4];
#pragma unroll
            for (int r = 0; r < 4; r++) pk[r] = f2bf(fmaxf(acc[n][r], 0.f));
            *(uint2*)(ee1h + ibase + (size_t)sp * 64 + co_base + lq * 4) = *(const uint2*)pk;
        }
        return;
    }

    // -------------------------------- gam role
    unsigned short* la = shb;            // 64x128 bf16, 16 KB
    unsigned short* lp = shb + 8192;     // 64x64 bf16, 8 KB
    int p0 = (bid - 512) * 64;
    int b = p0 >> 14;
    int s0 = p0 & (HW - 1);

    const unsigned short* src = gxgyh + (size_t)p0 * 128;
    for (int i = tid; i < 1024; i += 256) {
        int px = i >> 4, cg = i & 15;
        uint4 v = *(const uint4*)(src + px * 128 + cg * 8);
        *(uint4*)(la + px * 128 + ((cg ^ (px & 15)) * 8)) = v;
    }
    int co_base = wv * 16;
    s8v af[4];
#pragma unroll
    for (int h = 0; h < 4; h++)
        af[h] = *(const s8v*)(w1m + (co_base + l15) * 128 + h * 32 + lq * 8);
    f4v bv = *(const f4v*)(b1 + co_base + lq * 4);
    f4v acc[4];
#pragma unroll
    for (int n = 0; n < 4; n++) acc[n] = bv;
    __syncthreads();
#pragma unroll
    for (int n = 0; n < 4; n++) {
        const unsigned short* tp = la + (n * 16 + l15) * 128;
#pragma unroll
        for (int h = 0; h < 4; h++) {
            s8v bb = *(const s8v*)(tp + (((h * 4 + lq) ^ l15) * 8));
            acc[n] = __builtin_amdgcn_mfma_f32_16x16x32_bf16(af[h], bb, acc[n], 0, 0, 0);
        }
    }
    int co = co_base + lq * 4;
    int og = co >> 3;
#pragma unroll
    for (int n = 0; n < 4; n++) {
        int px = n * 16 + l15;
        alignas(8) unsigned short pk[4];
#pragma unroll
        for (int r = 0; r < 4; r++) pk[r] = f2bf(fmaxf(acc[n][r], 0.f));
        *(uint2*)(lp + px * 64 + ((og ^ (px & 7)) * 8) + (co & 7)) = *(const uint2*)pk;
    }
    __syncthreads();
    s8v af2[2];
#pragma unroll
    for (int h = 0; h < 2; h++)
        af2[h] = *(const s8v*)(w2m + l15 * 64 + h * 32 + lq * 8);
    f4v acc2 = *(const f4v*)(b2 + lq * 4);
    int px2 = wv * 16 + l15;
    const unsigned short* tp2 = lp + px2 * 64;
#pragma unroll
    for (int h = 0; h < 2; h++) {
        s8v bb = *(const s8v*)(tp2 + (((h * 4 + lq) ^ (px2 & 7)) * 8));
        acc2 = __builtin_amdgcn_mfma_f32_16x16x32_bf16(af2[h], bb, acc2, 0, 0, 0);
    }
    float* op = ga2 + (size_t)b * 16 * HW + s0 + px2;
#pragma unroll
    for (int r = 0; r < 4; r++)
        op[(lq * 4 + r) * HW] = fmaxf(acc2[r], 0.f);
}

// ---------------------------------------------------------------------------
// K_CD: fused consistency-detector + final 3x3 conv [64][64] MFMA + epilogue.
// Per block (8x8 tile, 4 waves): wave wv's lane (l15,lq) computes pixel
// wv*16+l15's cd-conv for co-quad lq (3x3 [16][16] from ga2 halo in LDS),
// shfl-reduces the 1x1 [1][16] + cmPart sum across lq, sigmoid -> lew[64].
// Then standard MFMA conv; epilogue out = x + alpha*lew[px]*acc.
__global__ __launch_bounds__(256, 2)
void k_CD(const unsigned short* __restrict__ inh,
          const unsigned short* __restrict__ wh,
          const float* __restrict__ bias,
          const float* __restrict__ ga2,
          const float* __restrict__ cd_w1t, const float* __restrict__ cd_b1,
          const float* __restrict__ cd_w2, const float* __restrict__ cd_b2,
          const float* __restrict__ cmPart,
          float* __restrict__ outf,
          const float* __restrict__ x,
          const float* __restrict__ alpha_p) {
    __shared__ unsigned short tile[100 * 64];   // 12.8 KB
    __shared__ float lg[100 * 17];              // 6.8 KB ga2 halo (pad 17)
    __shared__ float lew[64];
    int tid = threadIdx.x;
    int x0 = blockIdx.x * 8, y0 = blockIdx.y * 8;
    int b = blockIdx.z;
    const size_t ibase = (size_t)b * HW * 64;

    for (int i = tid; i < 800; i += 256) {
        int py = i / 80;
        int r = i - py * 80;
        int px = r >> 3, cg = r & 7;
        int gy = y0 - 1 + py, gx = x0 - 1 + px;
        uint4 v = {0u, 0u, 0u, 0u};
        if (gy >= 0 && gy < Hd && gx >= 0 && gx < Wd)
            v = *(const uint4*)(inh + ibase + (size_t)(gy * Wd + gx) * 64 + cg * 8);
        int rowlin = py * 10 + px;
        int scg = cg ^ (rowlin & 7);
        *(uint4*)(tile + rowlin * 64 + scg * 8) = v;
    }
    for (int i = tid; i < 1600; i += 256) {
        int ci = i / 100;
        int r = i - ci * 100;
        int yy = r / 10, xx = r - yy * 10;
        int gy = y0 - 1 + yy, gx = x0 - 1 + xx;
        float v = (gy >= 0 && gy < Hd && gx >= 0 && gx < Wd)
                      ? ga2[((size_t)b * 16 + ci) * HW + gy * Wd + gx] : 0.f;
        lg[r * 17 + ci] = v;
    }

    int lane = tid & 63;
    int wv = tid >> 6;
    int l15 = lane & 15, lq = lane >> 4;
    int co_base = wv * 16;
    s8v af[9][2];
#pragma unroll
    for (int t = 0; t < 9; t++)
#pragma unroll
        for (int h = 0; h < 2; h++)
            af[t][h] = *(const s8v*)(wh + ((t * 64 + co_base + l15) * 64 + h * 32 + lq * 8));
    f4v bv = *(const f4v*)(bias + co_base + lq * 4);
    f4v acc[4];
#pragma unroll
    for (int n = 0; n < 4; n++) acc[n] = bv;
    __syncthreads();

    // ---- ew for pixel (wv*16 + l15), co-quad lq
    {
        int pxl = wv * 16 + l15;            // 0..63
        int py = pxl >> 3, pxx = pxl & 7;
        float ae0 = cd_b1[lq * 4 + 0], ae1 = cd_b1[lq * 4 + 1];
        float ae2 = cd_b1[lq * 4 + 2], ae3 = cd_b1[lq * 4 + 3];
        for (int ci = 0; ci < 16; ci++) {
            float pv[9];
#pragma unroll
            for (int dy = 0; dy < 3; dy++)
#pragma unroll
                for (int dx = 0; dx < 3; dx++)
                    pv[dy * 3 + dx] = lg[((py + dy) * 10 + pxx + dx) * 17 + ci];
            const float* wp = cd_w1t + ci * 144 + lq * 4;
#pragma unroll
            for (int t = 0; t < 9; t++) {
                ae0 = fmaf(pv[t], wp[t * 16 + 0], ae0);
                ae1 = fmaf(pv[t], wp[t * 16 + 1], ae1);
                ae2 = fmaf(pv[t], wp[t * 16 + 2], ae2);
                ae3 = fmaf(pv[t], wp[t * 16 + 3], ae3);
            }
        }
        float ep = fmaxf(ae0, 0.f) * cd_w2[lq * 4 + 0]
                 + fmaxf(ae1, 0.f) * cd_w2[lq * 4 + 1]
                 + fmaxf(ae2, 0.f) * cd_w2[lq * 4 + 2]
                 + fmaxf(ae3, 0.f) * cd_w2[lq * 4 + 3];
        int sp = (y0 + py) * Wd + x0 + pxx;
        float cp = 0.f;
#pragma unroll
        for (int q = 0; q < 4; q++)
            cp += cmPart[(size_t)((b << 4) + lq * 4 + q) * HW + sp];
        ep += __shfl_xor(ep, 16);
        ep += __shfl_xor(ep, 32);
        cp += __shfl_xor(cp, 16);
        cp += __shfl_xor(cp, 32);
        float sig = rcpf(1.f + __expf(-(cd_b2[0] + ep)));
        if (lane < 16) lew[wv * 16 + lane] = sig * cp;
    }
    __syncthreads();

#pragma unroll
    for (int n = 0; n < 4; n++) {
        int px = n * 16 + l15;
        int pyy = px >> 3, pxx = px & 7;
#pragma unroll
        for (int dy = 0; dy < 3; dy++) {
#pragma unroll
            for (int dx = 0; dx < 3; dx++) {
                int rowlin = (pyy + dy) * 10 + (pxx + dx);
                int sw = rowlin & 7;
                const unsigned short* tp = tile + rowlin * 64;
                s8v b0 = *(const s8v*)(tp + (lq ^ sw) * 8);
                s8v b1v = *(const s8v*)(tp + ((4 + lq) ^ sw) * 8);
                int t = dy * 3 + dx;
                acc[n] = __builtin_amdgcn_mfma_f32_16x16x32_bf16(af[t][0], b0, acc[n], 0, 0, 0);
                acc[n] = __builtin_amdgcn_mfma_f32_16x16x32_bf16(af[t][1], b1v, acc[n], 0, 0, 0);
            }
        }
    }
    float alp = alpha_p[0];
#pragma unroll
    for (int n = 0; n < 4; n++) {
        int px = n * 16 + l15;
        int sp = (y0 + (px >> 3)) * Wd + x0 + (px & 7);
        float ae = alp * lew[px];
#pragma unroll
        for (int r = 0; r < 4; r++) {
            size_t o = (size_t)(b * 64 + co_base + lq * 4 + r) * HW + sp;
            outf[o] = fmaf(ae, acc[n][r], x[o]);
        }
    }
}

// ---------------------------------------------------------------------------
extern "C" void kernel_launch(void* const* d_in, const int* in_sizes, int n_in,
                              void* d_out, int out_size, void* d_ws, size_t ws_size,
                              hipStream_t stream) {
    const float* x     = (const float*)d_in[0];
    const float* wgx   = (const float*)d_in[1];
    const float* wgy   = (const float*)d_in[2];
    const float* ga_w1 = (const float*)d_in[3];
    const float* ga_b1 = (const float*)d_in[4];
    const float* ga_w2 = (const float*)d_in[5];
    const float* ga_b2 = (const float*)d_in[6];
    const float* cd_w1 = (const float*)d_in[7];
    const float* cd_b1 = (const float*)d_in[8];
    const float* cd_w2 = (const float*)d_in[9];
    const float* cd_b2 = (const float*)d_in[10];
    const float* ec_w1 = (const float*)d_in[11];
    const float* ec_b1 = (const float*)d_in[12];
    const float* ec_w2 = (const float*)d_in[13];
    const float* ec_b2 = (const float*)d_in[14];
    const float* alpha = (const float*)d_in[15];
    float* out = (float*)d_out;
    float* ws  = (float*)d_ws;

    const size_t N = 2 * 64 * HW;   // 2,097,152 floats

    // buffer plan:
    unsigned short* gxgyh = (unsigned short*)ws;  // 2*HW px * 128ch bf16 = N floats
    float* ga2    = ws + N;                       // 524288 floats
    float* cmPart = ga2 + 2 * 16 * HW;            // 32 slices x HW = 524288 floats
    float* cd_w1t = cmPart + 32 * HW;             // 2304
    unsigned short* w1h = (unsigned short*)(cd_w1t + 2304);  // 36864 shorts
    unsigned short* w2h = w1h + 36864;                       // 36864
    unsigned short* w1m = w2h + 36864;                       // 8192
    unsigned short* w2m = w1m + 8192;                        // 1024
    unsigned short* xh   = (unsigned short*)(ws + 2 * N);    // 2M shorts
    unsigned short* ee1h = xh + N;                           // 2M shorts

    k_A<<<2893, 256, 0, stream>>>(x, wgx, wgy, ga_w1, ga_w2, cd_w1, ec_w1, ec_w2,
                                  gxgyh, cmPart, xh, w1m, w2m, cd_w1t, w1h, w2h);
    k_B<<<1024, 256, 0, stream>>>(xh, w1h, ec_b1, ee1h,
                                  gxgyh, w1m, ga_b1, w2m, ga_b2, ga2);
    k_CD<<<dim3(16, 16, 2), 256, 0, stream>>>(ee1h, w2h, ec_b2, ga2,
                                              cd_w1t, cd_b1, cd_w2, cd_b2,
                                              cmPart, out, x, alpha);
}